// Round 8
// baseline (394.264 us; speedup 1.0000x reference)
//
#include <hip/hip_runtime.h>

typedef _Float16 f16;
typedef _Float16 f16x8 __attribute__((ext_vector_type(8)));
typedef _Float16 f16x4 __attribute__((ext_vector_type(4)));
typedef _Float16 f16x2 __attribute__((ext_vector_type(2)));
typedef float f32x4 __attribute__((ext_vector_type(4)));

#define GLOAD_LDS16(g, l) \
    __builtin_amdgcn_global_load_lds((const __attribute__((address_space(1))) void*)(g), \
                                     (__attribute__((address_space(3))) void*)(l), 16, 0, 0)

__device__ __forceinline__ f16x2 cvt_pk_f16(float a, float b) {
    return __builtin_bit_cast(f16x2, __builtin_amdgcn_cvt_pkrtz(a, b));
}

// 0.125 * log2(e): Qp is pre-scaled by this so attn uses exp2(acc) directly
#define SC_LOG2E 0.180336880f

// ---------------- q,k,v f32 -> f16 ----------------
__global__ __launch_bounds__(256) void cvt3_kernel(const float* __restrict__ q,
        const float* __restrict__ k, const float* __restrict__ v, f16* __restrict__ out) {
    const int z = blockIdx.y;
    const float* src = (z == 0) ? q : (z == 1) ? k : v;
    const size_t i = ((size_t)blockIdx.x * 256 + threadIdx.x) * 8;
    float4 a = *(const float4*)&src[i], b2 = *(const float4*)&src[i + 4];
    f16x8 h;
    h[0] = (f16)a.x; h[1] = (f16)a.y; h[2] = (f16)a.z; h[3] = (f16)a.w;
    h[4] = (f16)b2.x; h[5] = (f16)b2.y; h[6] = (f16)b2.z; h[7] = (f16)b2.w;
    *(f16x8*)&out[(size_t)z * 8388608 + i] = h;
}

// ---------------- all 4 weight transposes ----------------
__global__ void transpose_w_kernel(const float* __restrict__ Wq, const float* __restrict__ Wk,
        const float* __restrict__ Wv, const float* __restrict__ Wo, f16* __restrict__ out) {
    const int z = blockIdx.y;
    int t = blockIdx.x * 256 + threadIdx.x;
    int n = t >> 10, d = t & 1023;
    float val;
    if (z < 3) {
        const float* W = (z == 0) ? Wq : (z == 1) ? Wk : Wv;
        val = W[((size_t)(n >> 6) * 1024 + d) * 64 + (n & 63)];
    } else {
        val = Wo[(size_t)d * 1024 + n];
    }
    out[(size_t)z * 1048576 + (size_t)n * 1024 + d] = (f16)val;
}

// ---------------- mask int32 -> bitmask ----------------
__global__ void maskbits_kernel(const int* __restrict__ mask, unsigned* __restrict__ bits) {
    int t = blockIdx.x * 256 + threadIdx.x;   // 262144 words total
    const int4* src = (const int4*)mask + (size_t)t * 8;
    unsigned w = 0;
#pragma unroll
    for (int i = 0; i < 8; ++i) {
        int4 v = src[i];
        w |= (v.x != 0 ? 1u : 0u) << (i * 4 + 0);
        w |= (v.y != 0 ? 1u : 0u) << (i * 4 + 1);
        w |= (v.z != 0 ? 1u : 0u) << (i * 4 + 2);
        w |= (v.w != 0 ? 1u : 0u) << (i * 4 + 3);
    }
    bits[t] = w;
}

// ---------------- fused Q/K/V projection GEMM, 128x128, K=1024, XCD-colocated -----------
__global__ __launch_bounds__(256) void proj_kernel(const f16* __restrict__ Ah,
        const f16* __restrict__ Wt, f16* __restrict__ Outp) {
    __shared__ __align__(16) f16 As[128][64];
    __shared__ __align__(16) f16 Bs[128][64];
    const int id = blockIdx.x;
    const int z = id >> 9;
    const int id2 = id & 511;
    const int m0 = ((id2 & 7) * 8 + ((id2 >> 3) & 7)) * 128;
    const int n0 = (id2 >> 6) * 128;
    const f16* A = Ah + (size_t)z * 8388608;
    const f16* Bt = Wt + (size_t)z * 1048576;
    f16* Out = Outp + (size_t)z * 8388608;
    const int tid = threadIdx.x, lane = tid & 63;
    const int w = tid >> 6, wr = w >> 1, wc = w & 1;

    f32x4 acc[4][4];
#pragma unroll
    for (int mi = 0; mi < 4; ++mi)
#pragma unroll
        for (int ni = 0; ni < 4; ++ni) acc[mi][ni] = (f32x4){0.f, 0.f, 0.f, 0.f};

    for (int kt = 0; kt < 16; ++kt) {
        const int k0 = kt * 64;
#pragma unroll
        for (int seg = 0; seg < 4; ++seg) {
            const int ch = seg * 256 + tid, r = ch >> 3, c = ch & 7;
            GLOAD_LDS16(&A[(size_t)(m0 + r) * 1024 + k0 + (c ^ (r & 7)) * 8],
                        (char*)&As[0][0] + (seg * 256 + w * 64) * 16);
            GLOAD_LDS16(&Bt[(size_t)(n0 + r) * 1024 + k0 + (c ^ (r & 7)) * 8],
                        (char*)&Bs[0][0] + (seg * 256 + w * 64) * 16);
        }
        __syncthreads();
#pragma unroll
        for (int ks = 0; ks < 2; ++ks) {
            const int slot = ks * 4 + (lane >> 4);
            f16x8 af[4], bf[4];
#pragma unroll
            for (int mi = 0; mi < 4; ++mi) {
                const int row = wr * 64 + mi * 16 + (lane & 15);
                af[mi] = *(const f16x8*)&As[row][(slot ^ (row & 7)) * 8];
            }
#pragma unroll
            for (int ni = 0; ni < 4; ++ni) {
                const int row = wc * 64 + ni * 16 + (lane & 15);
                bf[ni] = *(const f16x8*)&Bs[row][(slot ^ (row & 7)) * 8];
            }
#pragma unroll
            for (int mi = 0; mi < 4; ++mi)
#pragma unroll
                for (int ni = 0; ni < 4; ++ni)
                    acc[mi][ni] = __builtin_amdgcn_mfma_f32_16x16x32_f16(af[mi], bf[ni], acc[mi][ni], 0, 0, 0);
        }
        __syncthreads();
    }

    const float sc = (z == 0) ? SC_LOG2E : 1.0f;
#pragma unroll
    for (int mi = 0; mi < 4; ++mi)
#pragma unroll
        for (int ni = 0; ni < 4; ++ni) {
            const int row0 = m0 + wr * 64 + mi * 16 + ((lane >> 4) << 2);
            const int col = n0 + wc * 64 + ni * 16 + (lane & 15);
            const int h = col >> 6, kk = col & 63;
            const int b = row0 >> 10, l0 = row0 & 1023;
            if (z < 2) {
#pragma unroll
                for (int r = 0; r < 4; ++r)
                    Out[(((size_t)(b * 16 + h) * 1024) + l0 + r) * 64 + kk] = (f16)(acc[mi][ni][r] * sc);
            } else {
                f16x4 hv;
#pragma unroll
                for (int r = 0; r < 4; ++r) hv[r] = (f16)acc[mi][ni][r];
                *(f16x4*)&Out[((size_t)(b * 16 + h) * 64 + kk) * 1024 + l0] = hv;
            }
        }
}

// ---------------- output projection GEMM ----------------
__global__ __launch_bounds__(256) void out_kernel(const f16* __restrict__ A,
        const f16* __restrict__ Bt, float* __restrict__ O, const float* __restrict__ bias) {
    __shared__ __align__(16) f16 As[128][64];
    __shared__ __align__(16) f16 Bs[128][64];
    const int id2 = blockIdx.x;
    const int m0 = ((id2 & 7) * 8 + ((id2 >> 3) & 7)) * 128;
    const int n0 = (id2 >> 6) * 128;
    const int tid = threadIdx.x, lane = tid & 63;
    const int w = tid >> 6, wr = w >> 1, wc = w & 1;

    f32x4 acc[4][4];
#pragma unroll
    for (int mi = 0; mi < 4; ++mi)
#pragma unroll
        for (int ni = 0; ni < 4; ++ni) acc[mi][ni] = (f32x4){0.f, 0.f, 0.f, 0.f};

    for (int kt = 0; kt < 16; ++kt) {
        const int k0 = kt * 64;
#pragma unroll
        for (int seg = 0; seg < 4; ++seg) {
            const int ch = seg * 256 + tid, r = ch >> 3, c = ch & 7;
            GLOAD_LDS16(&A[(size_t)(m0 + r) * 1024 + k0 + (c ^ (r & 7)) * 8],
                        (char*)&As[0][0] + (seg * 256 + w * 64) * 16);
            GLOAD_LDS16(&Bt[(size_t)(n0 + r) * 1024 + k0 + (c ^ (r & 7)) * 8],
                        (char*)&Bs[0][0] + (seg * 256 + w * 64) * 16);
        }
        __syncthreads();
#pragma unroll
        for (int ks = 0; ks < 2; ++ks) {
            const int slot = ks * 4 + (lane >> 4);
            f16x8 af[4], bf[4];
#pragma unroll
            for (int mi = 0; mi < 4; ++mi) {
                const int row = wr * 64 + mi * 16 + (lane & 15);
                af[mi] = *(const f16x8*)&As[row][(slot ^ (row & 7)) * 8];
            }
#pragma unroll
            for (int ni = 0; ni < 4; ++ni) {
                const int row = wc * 64 + ni * 16 + (lane & 15);
                bf[ni] = *(const f16x8*)&Bs[row][(slot ^ (row & 7)) * 8];
            }
#pragma unroll
            for (int mi = 0; mi < 4; ++mi)
#pragma unroll
                for (int ni = 0; ni < 4; ++ni)
                    acc[mi][ni] = __builtin_amdgcn_mfma_f32_16x16x32_f16(af[mi], bf[ni], acc[mi][ni], 0, 0, 0);
        }
        __syncthreads();
    }

#pragma unroll
    for (int mi = 0; mi < 4; ++mi)
#pragma unroll
        for (int ni = 0; ni < 4; ++ni) {
            const int row0 = m0 + wr * 64 + mi * 16 + ((lane >> 4) << 2);
            const int col = n0 + wc * 64 + ni * 16 + (lane & 15);
            const float bb = bias[col];
#pragma unroll
            for (int r = 0; r < 4; ++r)
                __builtin_nontemporal_store(acc[mi][ni][r] + bb, &O[(size_t)(row0 + r) * 1024 + col]);
        }
}

// ---------------- single-sweep fused attention: full-P in LDS, K/V direct from L2 -------
// QBLK=32. Waves: g = w&1 (q-group of 16), h2 = w>>1 (k-half).
__global__ __launch_bounds__(256) void attn_fused_kernel(const f16* __restrict__ Qp,
        const f16* __restrict__ Kp, const f16* __restrict__ VpT,
        const unsigned* __restrict__ bits, float* __restrict__ attn, f16* __restrict__ headcat) {
    __shared__ __align__(16) f16 Ps[32][1024];        // 64 KB, 8B-slot XOR swizzle
    __shared__ unsigned bm[32][32];                   // word w at w ^ ((row&7)<<2)
    __shared__ __align__(16) float LUTf[16][4];
    __shared__ __align__(16) f16 LUTh[16][4];
    __shared__ float lsum2[2][2][16];
    __shared__ float rlS[32];
    __shared__ float red[2][16][68];                  // cross-wave PV reduce

    const int bh = blockIdx.x & 127, m0 = (blockIdx.x >> 7) * 32;
    const int b = bh >> 4, h = bh & 15;
    const int tid = threadIdx.x, lane = tid & 63, w = tid >> 6;
    const int g = w & 1, h2 = w >> 1;
    const int l15 = lane & 15, t4 = lane >> 4;
    const f16* Qbase = Qp + (size_t)bh * 65536;
    const f16* Kbase = Kp + (size_t)bh * 65536;
    const f16* Vbase = VpT + (size_t)bh * 65536;

    if (tid < 16) {
#pragma unroll
        for (int i = 0; i < 4; ++i) {
            const float on = ((tid >> i) & 1) ? 1.0f : 0.0f;
            LUTf[tid][i] = on;
            LUTh[tid][i] = (f16)on;
        }
    }
    {   // bm: 32 rows x 128B, 16B chunks, source pre-swizzled
        const int r = tid >> 3, c = tid & 7;
        GLOAD_LDS16((const char*)&bits[((size_t)b * 1024 + m0 + r) * 32] + (c ^ (r & 7)) * 16,
                    (char*)&bm[0][0] + (w * 64) * 16);
    }

    // Q fragments in registers (held whole kernel)
    const int qrow = m0 + g * 16 + l15;
    f16x8 af0 = *(const f16x8*)&Qbase[(size_t)qrow * 64 + t4 * 8];
    f16x8 af1 = *(const f16x8*)&Qbase[(size_t)qrow * 64 + 32 + t4 * 8];

    const int row = g * 16 + l15;                  // local q-row this thread owns (QK^T)
    const int swb = (row & 7) << 2;
    const int swz = (row & 7) << 1;
    float lsum = 0.f;

    // -------- QK^T sweep over this wave's 8 j-tiles, reg-dbuf K frags --------
    const int j0 = h2 * 8;
    f16x8 bf[2][4][2];
#pragma unroll
    for (int ni = 0; ni < 4; ++ni)
#pragma unroll
        for (int ks = 0; ks < 2; ++ks)
            bf[0][ni][ks] = *(const f16x8*)&Kbase[(size_t)(j0 * 64 + ni * 16 + l15) * 64 + ks * 32 + t4 * 8];

    __syncthreads();   // bm ready (gload_lds drained)

#pragma unroll
    for (int jj = 0; jj < 8; ++jj) {
        const int j = j0 + jj;
        if (jj < 7) {
#pragma unroll
            for (int ni = 0; ni < 4; ++ni)
#pragma unroll
                for (int ks = 0; ks < 2; ++ks)
                    bf[(jj + 1) & 1][ni][ks] = *(const f16x8*)&Kbase[(size_t)((j + 1) * 64 + ni * 16 + l15) * 64 + ks * 32 + t4 * 8];
        }
        f32x4 acc[4];
#pragma unroll
        for (int ni = 0; ni < 4; ++ni) acc[ni] = (f32x4){0.f, 0.f, 0.f, 0.f};
#pragma unroll
        for (int ni = 0; ni < 4; ++ni) {
            acc[ni] = __builtin_amdgcn_mfma_f32_16x16x32_f16(bf[jj & 1][ni][0], af0, acc[ni], 0, 0, 0);
            acc[ni] = __builtin_amdgcn_mfma_f32_16x16x32_f16(bf[jj & 1][ni][1], af1, acc[ni], 0, 0, 0);
        }
#pragma unroll
        for (int ni = 0; ni < 4; ++ni) {
            const unsigned word = bm[row][(2 * j + (ni >> 1)) ^ swb];
            const unsigned nib = (word >> (((ni & 1) << 4) + t4 * 4)) & 15u;
            const float4 mf = *(const float4*)&LUTf[nib][0];
            const float e0 = exp2f(acc[ni][0]), e1 = exp2f(acc[ni][1]);
            const float e2 = exp2f(acc[ni][2]), e3 = exp2f(acc[ni][3]);
            lsum = fmaf(e0, mf.x, lsum); lsum = fmaf(e1, mf.y, lsum);
            lsum = fmaf(e2, mf.z, lsum); lsum = fmaf(e3, mf.w, lsum);
            const f16x4 mh = *(const f16x4*)&LUTh[nib][0];
            f16x2 p01 = cvt_pk_f16(e0, e1) * (f16x2){mh[0], mh[1]};
            f16x2 p23 = cvt_pk_f16(e2, e3) * (f16x2){mh[2], mh[3]};
            f16x4 pw; pw[0] = p01[0]; pw[1] = p01[1]; pw[2] = p23[0]; pw[3] = p23[1];
            const int col4 = j * 16 + ni * 4 + t4;
            *(f16x4*)((char*)&Ps[0][0] + row * 2048 + ((col4 ^ swz) << 3)) = pw;
        }
    }

    // -------- lsum reduce -> rl --------
    lsum += __shfl_xor(lsum, 16);
    lsum += __shfl_xor(lsum, 32);
    if (lane < 16) lsum2[h2][g][lane] = lsum;
    __syncthreads();
    if (tid < 32) rlS[tid] = 1.0f / (lsum2[0][tid >> 4][tid & 15] + lsum2[1][tid >> 4][tid & 15]);
    __syncthreads();

    // -------- attn store: p_un * rl, fully coalesced nt, drains under PV --------
    {
        const int srow = tid >> 3, tcol = tid & 7;
        const float rl = rlS[srow];
        const int sswz = (srow & 7) << 1;
        float* aB = attn + (size_t)(b * 1024 + m0 + srow) * 16384 + h * 1024;
#pragma unroll
        for (int i = 0; i < 32; ++i) {
            const int col4 = tcol + i * 8;
            const f16x4 hv = *(const f16x4*)((const char*)&Ps[0][0] + srow * 2048 + ((col4 ^ sswz) << 3));
            f32x4 fv = {(float)hv[0] * rl, (float)hv[1] * rl, (float)hv[2] * rl, (float)hv[3] * rl};
            __builtin_nontemporal_store(fv, (f32x4*)&aB[col4 * 4]);
        }
    }

    // -------- PV over this wave's 16 kk-tiles, reg-dbuf V frags --------
    f32x4 accP[4];
#pragma unroll
    for (int ni = 0; ni < 4; ++ni) accP[ni] = (f32x4){0.f, 0.f, 0.f, 0.f};
    const int kk0 = h2 * 16;
    f16x8 vf[2][4];
#pragma unroll
    for (int ni = 0; ni < 4; ++ni)
        vf[0][ni] = *(const f16x8*)&Vbase[(size_t)(ni * 16 + l15) * 1024 + kk0 * 32 + t4 * 8];
#pragma unroll
    for (int t = 0; t < 16; ++t) {
        const int kk = kk0 + t;
        if (t < 15) {
#pragma unroll
            for (int ni = 0; ni < 4; ++ni)
                vf[(t + 1) & 1][ni] = *(const f16x8*)&Vbase[(size_t)(ni * 16 + l15) * 1024 + (kk + 1) * 32 + t4 * 8];
        }
        const int prow = g * 16 + l15;
        const int col4 = kk * 8 + t4 * 2;
        const f16x8 pf = *(const f16x8*)((const char*)&Ps[0][0] + prow * 2048 + ((col4 ^ ((prow & 7) << 1)) << 3));
#pragma unroll
        for (int ni = 0; ni < 4; ++ni)
            accP[ni] = __builtin_amdgcn_mfma_f32_16x16x32_f16(pf, vf[t & 1][ni], accP[ni], 0, 0, 0);
    }

    // -------- cross-wave (k-half) reduce, scale by rl, write hc --------
    if (h2 == 1) {
#pragma unroll
        for (int ni = 0; ni < 4; ++ni)
#pragma unroll
            for (int r = 0; r < 4; ++r)
                red[g][t4 * 4 + r][ni * 16 + l15] = accP[ni][r];
    }
    __syncthreads();
    if (h2 == 0) {
#pragma unroll
        for (int ni = 0; ni < 4; ++ni)
#pragma unroll
            for (int r = 0; r < 4; ++r) {
                const int qr = t4 * 4 + r;
                const float val = (accP[ni][r] + red[g][qr][ni * 16 + l15]) * rlS[g * 16 + qr];
                headcat[(size_t)(b * 1024 + m0 + g * 16 + qr) * 1024 + h * 64 + ni * 16 + l15] = (f16)val;
            }
    }
}

extern "C" void kernel_launch(void* const* d_in, const int* in_sizes, int n_in,
                              void* d_out, int out_size, void* d_ws, size_t ws_size,
                              hipStream_t stream) {
    const float* q = (const float*)d_in[0];
    const float* k = (const float*)d_in[1];
    const float* v = (const float*)d_in[2];
    const int* mask = (const int*)d_in[3];
    const float* Wq = (const float*)d_in[4];
    const float* Wk = (const float*)d_in[5];
    const float* Wv = (const float*)d_in[6];
    const float* Wo = (const float*)d_in[7];
    const float* bo = (const float*)d_in[8];

    float* out0 = (float*)d_out;                  // [8,1024,1024]
    float* attn = out0 + (size_t)8 * 1024 * 1024; // [8,1024,16384]

    char* ws = (char*)d_ws;
    f16* wt   = (f16*)(ws + ((size_t)0 << 20));   // wqt,wkt,wvt,wot contiguous: 8 MiB
    f16* qh   = (f16*)(ws + ((size_t)8 << 20));   // q,k,v f16 contiguous: 48 MiB
    f16* Qp   = (f16*)(ws + ((size_t)56 << 20));  // Qp,Kp,VpT contiguous: 48 MiB
    f16* Kp   = (f16*)(ws + ((size_t)72 << 20));
    f16* VpT  = (f16*)(ws + ((size_t)88 << 20));
    f16* hc   = (f16*)(ws + ((size_t)104 << 20)); // [B*L, 1024] f16
    unsigned* bits = (unsigned*)(ws + ((size_t)120 << 20)); // 1 MiB bitmask
    f16* wot  = wt + (size_t)3 * 1048576;

    cvt3_kernel<<<dim3(4096, 3), 256, 0, stream>>>(q, k, v, qh);
    transpose_w_kernel<<<dim3(4096, 4), 256, 0, stream>>>(Wq, Wk, Wv, Wo, wt);
    maskbits_kernel<<<1024, 256, 0, stream>>>(mask, bits);

    proj_kernel<<<1536, 256, 0, stream>>>(qh, wt, Qp);

    attn_fused_kernel<<<4096, 256, 0, stream>>>(Qp, Kp, VpT, bits, attn, hc);

    out_kernel<<<512, 256, 0, stream>>>(hc, wot, out0, bo);
}

// Round 9
// 360.798 us; speedup vs baseline: 1.0928x; 1.0928x over previous
//
#include <hip/hip_runtime.h>

typedef _Float16 f16;
typedef _Float16 f16x8 __attribute__((ext_vector_type(8)));
typedef _Float16 f16x4 __attribute__((ext_vector_type(4)));
typedef _Float16 f16x2 __attribute__((ext_vector_type(2)));
typedef float f32x4 __attribute__((ext_vector_type(4)));

#define GLOAD_LDS16(g, l) \
    __builtin_amdgcn_global_load_lds((const __attribute__((address_space(1))) void*)(g), \
                                     (__attribute__((address_space(3))) void*)(l), 16, 0, 0)

__device__ __forceinline__ f16x2 cvt_pk_f16(float a, float b) {
    return __builtin_bit_cast(f16x2, __builtin_amdgcn_cvt_pkrtz(a, b));
}

// 0.125 * log2(e): Qp is pre-scaled by this so attn uses exp2(acc) directly
#define SC_LOG2E 0.180336880f

// ---------------- q,k,v f32 -> f16 ----------------
__global__ __launch_bounds__(256) void cvt3_kernel(const float* __restrict__ q,
        const float* __restrict__ k, const float* __restrict__ v, f16* __restrict__ out) {
    const int z = blockIdx.y;
    const float* src = (z == 0) ? q : (z == 1) ? k : v;
    const size_t i = ((size_t)blockIdx.x * 256 + threadIdx.x) * 8;
    float4 a = *(const float4*)&src[i], b2 = *(const float4*)&src[i + 4];
    f16x8 h;
    h[0] = (f16)a.x; h[1] = (f16)a.y; h[2] = (f16)a.z; h[3] = (f16)a.w;
    h[4] = (f16)b2.x; h[5] = (f16)b2.y; h[6] = (f16)b2.z; h[7] = (f16)b2.w;
    *(f16x8*)&out[(size_t)z * 8388608 + i] = h;
}

// ---------------- all 4 weight transposes ----------------
__global__ void transpose_w_kernel(const float* __restrict__ Wq, const float* __restrict__ Wk,
        const float* __restrict__ Wv, const float* __restrict__ Wo, f16* __restrict__ out) {
    const int z = blockIdx.y;
    int t = blockIdx.x * 256 + threadIdx.x;
    int n = t >> 10, d = t & 1023;
    float val;
    if (z < 3) {
        const float* W = (z == 0) ? Wq : (z == 1) ? Wk : Wv;
        val = W[((size_t)(n >> 6) * 1024 + d) * 64 + (n & 63)];
    } else {
        val = Wo[(size_t)d * 1024 + n];
    }
    out[(size_t)z * 1048576 + (size_t)n * 1024 + d] = (f16)val;
}

// ---------------- mask int32 -> bitmask ----------------
__global__ void maskbits_kernel(const int* __restrict__ mask, unsigned* __restrict__ bits) {
    int t = blockIdx.x * 256 + threadIdx.x;   // 262144 words total
    const int4* src = (const int4*)mask + (size_t)t * 8;
    unsigned w = 0;
#pragma unroll
    for (int i = 0; i < 8; ++i) {
        int4 v = src[i];
        w |= (v.x != 0 ? 1u : 0u) << (i * 4 + 0);
        w |= (v.y != 0 ? 1u : 0u) << (i * 4 + 1);
        w |= (v.z != 0 ? 1u : 0u) << (i * 4 + 2);
        w |= (v.w != 0 ? 1u : 0u) << (i * 4 + 3);
    }
    bits[t] = w;
}

// ---------------- fused Q/K/V projection GEMM, 128x128, K=1024, XCD-colocated -----------
// z=0: Qp (scaled by SC_LOG2E), z=1: Kp, both [B,H,L,64]; z=2: VpT [B,H,64,L]
__global__ __launch_bounds__(256) void proj_kernel(const f16* __restrict__ Ah,
        const f16* __restrict__ Wt, f16* __restrict__ Outp) {
    __shared__ __align__(16) f16 As[128][64];
    __shared__ __align__(16) f16 Bs[128][64];
    const int id = blockIdx.x;
    const int z = id >> 9;
    const int id2 = id & 511;
    const int m0 = ((id2 & 7) * 8 + ((id2 >> 3) & 7)) * 128;
    const int n0 = (id2 >> 6) * 128;
    const f16* A = Ah + (size_t)z * 8388608;
    const f16* Bt = Wt + (size_t)z * 1048576;
    f16* Out = Outp + (size_t)z * 8388608;
    const int tid = threadIdx.x, lane = tid & 63;
    const int w = tid >> 6, wr = w >> 1, wc = w & 1;

    f32x4 acc[4][4];
#pragma unroll
    for (int mi = 0; mi < 4; ++mi)
#pragma unroll
        for (int ni = 0; ni < 4; ++ni) acc[mi][ni] = (f32x4){0.f, 0.f, 0.f, 0.f};

    for (int kt = 0; kt < 16; ++kt) {
        const int k0 = kt * 64;
#pragma unroll
        for (int seg = 0; seg < 4; ++seg) {
            const int ch = seg * 256 + tid, r = ch >> 3, c = ch & 7;
            GLOAD_LDS16(&A[(size_t)(m0 + r) * 1024 + k0 + (c ^ (r & 7)) * 8],
                        (char*)&As[0][0] + (seg * 256 + w * 64) * 16);
            GLOAD_LDS16(&Bt[(size_t)(n0 + r) * 1024 + k0 + (c ^ (r & 7)) * 8],
                        (char*)&Bs[0][0] + (seg * 256 + w * 64) * 16);
        }
        __syncthreads();
#pragma unroll
        for (int ks = 0; ks < 2; ++ks) {
            const int slot = ks * 4 + (lane >> 4);
            f16x8 af[4], bf[4];
#pragma unroll
            for (int mi = 0; mi < 4; ++mi) {
                const int row = wr * 64 + mi * 16 + (lane & 15);
                af[mi] = *(const f16x8*)&As[row][(slot ^ (row & 7)) * 8];
            }
#pragma unroll
            for (int ni = 0; ni < 4; ++ni) {
                const int row = wc * 64 + ni * 16 + (lane & 15);
                bf[ni] = *(const f16x8*)&Bs[row][(slot ^ (row & 7)) * 8];
            }
#pragma unroll
            for (int mi = 0; mi < 4; ++mi)
#pragma unroll
                for (int ni = 0; ni < 4; ++ni)
                    acc[mi][ni] = __builtin_amdgcn_mfma_f32_16x16x32_f16(af[mi], bf[ni], acc[mi][ni], 0, 0, 0);
        }
        __syncthreads();
    }

    const float sc = (z == 0) ? SC_LOG2E : 1.0f;
#pragma unroll
    for (int mi = 0; mi < 4; ++mi)
#pragma unroll
        for (int ni = 0; ni < 4; ++ni) {
            const int row0 = m0 + wr * 64 + mi * 16 + ((lane >> 4) << 2);
            const int col = n0 + wc * 64 + ni * 16 + (lane & 15);
            const int h = col >> 6, kk = col & 63;
            const int b = row0 >> 10, l0 = row0 & 1023;
            if (z < 2) {
#pragma unroll
                for (int r = 0; r < 4; ++r)
                    Out[(((size_t)(b * 16 + h) * 1024) + l0 + r) * 64 + kk] = (f16)(acc[mi][ni][r] * sc);
            } else {
                f16x4 hv;
#pragma unroll
                for (int r = 0; r < 4; ++r) hv[r] = (f16)acc[mi][ni][r];
                *(f16x4*)&Out[((size_t)(b * 16 + h) * 64 + kk) * 1024 + l0] = hv;
            }
        }
}

// ---------------- output projection GEMM ----------------
__global__ __launch_bounds__(256) void out_kernel(const f16* __restrict__ A,
        const f16* __restrict__ Bt, float* __restrict__ O, const float* __restrict__ bias) {
    __shared__ __align__(16) f16 As[128][64];
    __shared__ __align__(16) f16 Bs[128][64];
    const int id2 = blockIdx.x;
    const int m0 = ((id2 & 7) * 8 + ((id2 >> 3) & 7)) * 128;
    const int n0 = (id2 >> 6) * 128;
    const int tid = threadIdx.x, lane = tid & 63;
    const int w = tid >> 6, wr = w >> 1, wc = w & 1;

    f32x4 acc[4][4];
#pragma unroll
    for (int mi = 0; mi < 4; ++mi)
#pragma unroll
        for (int ni = 0; ni < 4; ++ni) acc[mi][ni] = (f32x4){0.f, 0.f, 0.f, 0.f};

    for (int kt = 0; kt < 16; ++kt) {
        const int k0 = kt * 64;
#pragma unroll
        for (int seg = 0; seg < 4; ++seg) {
            const int ch = seg * 256 + tid, r = ch >> 3, c = ch & 7;
            GLOAD_LDS16(&A[(size_t)(m0 + r) * 1024 + k0 + (c ^ (r & 7)) * 8],
                        (char*)&As[0][0] + (seg * 256 + w * 64) * 16);
            GLOAD_LDS16(&Bt[(size_t)(n0 + r) * 1024 + k0 + (c ^ (r & 7)) * 8],
                        (char*)&Bs[0][0] + (seg * 256 + w * 64) * 16);
        }
        __syncthreads();
#pragma unroll
        for (int ks = 0; ks < 2; ++ks) {
            const int slot = ks * 4 + (lane >> 4);
            f16x8 af[4], bf[4];
#pragma unroll
            for (int mi = 0; mi < 4; ++mi) {
                const int row = wr * 64 + mi * 16 + (lane & 15);
                af[mi] = *(const f16x8*)&As[row][(slot ^ (row & 7)) * 8];
            }
#pragma unroll
            for (int ni = 0; ni < 4; ++ni) {
                const int row = wc * 64 + ni * 16 + (lane & 15);
                bf[ni] = *(const f16x8*)&Bs[row][(slot ^ (row & 7)) * 8];
            }
#pragma unroll
            for (int mi = 0; mi < 4; ++mi)
#pragma unroll
                for (int ni = 0; ni < 4; ++ni)
                    acc[mi][ni] = __builtin_amdgcn_mfma_f32_16x16x32_f16(af[mi], bf[ni], acc[mi][ni], 0, 0, 0);
        }
        __syncthreads();
    }

#pragma unroll
    for (int mi = 0; mi < 4; ++mi)
#pragma unroll
        for (int ni = 0; ni < 4; ++ni) {
            const int row0 = m0 + wr * 64 + mi * 16 + ((lane >> 4) << 2);
            const int col = n0 + wc * 64 + ni * 16 + (lane & 15);
            const float bb = bias[col];
#pragma unroll
            for (int r = 0; r < 4; ++r)
                __builtin_nontemporal_store(acc[mi][ni][r] + bb, &O[(size_t)(row0 + r) * 1024 + col]);
        }
}

// ---------------- fused attention: swapped QK^T, counted-vmcnt pipeline in sweep 2 -------
__global__ __launch_bounds__(256) void attn_fused_kernel(const f16* __restrict__ Qp,
        const f16* __restrict__ Kp, const f16* __restrict__ VpT,
        const unsigned* __restrict__ bits, float* __restrict__ attn, f16* __restrict__ headcat) {
    __shared__ __align__(16) f16 Qs[128][64];
    __shared__ __align__(16) f16 Ks[2][64][64];
    __shared__ __align__(16) f16 Vs[2][64][64];       // double buffer (sweep 2)
    __shared__ __align__(16) f16 Ps[128][64];
    __shared__ unsigned bm[128][32];                  // word w stored at w ^ ((row&7)<<2)
    __shared__ __align__(16) float LUTf[16][4];
    __shared__ __align__(16) f16 LUTh[16][4];
    const int bh = blockIdx.x & 127, m0 = (blockIdx.x >> 7) * 128;
    const int b = bh >> 4, h = bh & 15;
    const int tid = threadIdx.x, lane = tid & 63, w = tid >> 6;
    const f16* Qbase = Qp + (size_t)bh * 65536;
    const f16* Kbase = Kp + (size_t)bh * 65536;
    const f16* Vbase = VpT + (size_t)bh * 65536;

    auto stageK = [&](int buf, int j) {
#pragma unroll
        for (int seg = 0; seg < 2; ++seg) {
            const int ch = seg * 256 + tid, r = ch >> 3, c = ch & 7;
            GLOAD_LDS16(&Kbase[(size_t)(j * 64 + r) * 64 + (c ^ (r & 7)) * 8],
                        (char*)&Ks[buf][0][0] + (seg * 256 + w * 64) * 16);
        }
    };
    auto stageV = [&](int buf, int j) {
#pragma unroll
        for (int seg = 0; seg < 2; ++seg) {
            const int ch = seg * 256 + tid, r = ch >> 3, c = ch & 7;
            GLOAD_LDS16(&Vbase[(size_t)r * 1024 + j * 64 + (c ^ (r & 7)) * 8],
                        (char*)&Vs[buf][0][0] + (seg * 256 + w * 64) * 16);
        }
    };

    if (tid < 16) {
#pragma unroll
        for (int i = 0; i < 4; ++i) {
            const float on = ((tid >> i) & 1) ? 1.0f : 0.0f;
            LUTf[tid][i] = on;
            LUTh[tid][i] = (f16)on;
        }
    }
    // prologue: Qs, bm (word-swizzled), K tile 0
#pragma unroll
    for (int seg = 0; seg < 4; ++seg) {
        const int ch = seg * 256 + tid, r = ch >> 3, c = ch & 7;
        GLOAD_LDS16(&Qbase[(size_t)(m0 + r) * 64 + (c ^ (r & 7)) * 8],
                    (char*)&Qs[0][0] + (seg * 256 + w * 64) * 16);
        GLOAD_LDS16((const char*)&bits[((size_t)b * 1024 + m0 + r) * 32] + (c ^ (r & 7)) * 16,
                    (char*)&bm[0][0] + (seg * 256 + w * 64) * 16);
    }
    stageK(0, 0);
    __syncthreads();

    float lsum[2] = {0.f, 0.f};
    const int kb0 = (lane >> 4) * 4;     // thread's contiguous 4-col base (swapped layout)

    // -------- sweep 1: l = sum_col exp2(s) * mask --------
    for (int j = 0; j < 16; ++j) {
        if (j < 15) stageK((j + 1) & 1, j + 1);

        f32x4 acc[2][4];
#pragma unroll
        for (int mi = 0; mi < 2; ++mi)
#pragma unroll
            for (int ni = 0; ni < 4; ++ni) acc[mi][ni] = (f32x4){0.f, 0.f, 0.f, 0.f};
        __builtin_amdgcn_s_setprio(1);
#pragma unroll
        for (int ks = 0; ks < 2; ++ks) {
            const int slot = ks * 4 + (lane >> 4);
            f16x8 af[2], bf[4];
#pragma unroll
            for (int mi = 0; mi < 2; ++mi) {
                const int row = w * 32 + mi * 16 + (lane & 15);
                af[mi] = *(const f16x8*)&Qs[row][(slot ^ (row & 7)) * 8];
            }
#pragma unroll
            for (int ni = 0; ni < 4; ++ni) {
                const int row = ni * 16 + (lane & 15);
                bf[ni] = *(const f16x8*)&Ks[j & 1][row][(slot ^ (row & 7)) * 8];
            }
            // swapped: acc = K-frag x Q-frag -> S^T (row=kcol, col=qrow)
#pragma unroll
            for (int mi = 0; mi < 2; ++mi)
#pragma unroll
                for (int ni = 0; ni < 4; ++ni)
                    acc[mi][ni] = __builtin_amdgcn_mfma_f32_16x16x32_f16(bf[ni], af[mi], acc[mi][ni], 0, 0, 0);
        }
        __builtin_amdgcn_s_setprio(0);

#pragma unroll
        for (int mi = 0; mi < 2; ++mi) {
            const int rowm = w * 32 + mi * 16 + (lane & 15);
            const int swb = (rowm & 7) << 2;
#pragma unroll
            for (int ni = 0; ni < 4; ++ni) {
                const unsigned word = bm[rowm][(2 * j + (ni >> 1)) ^ swb];
                const unsigned nib = (word >> (((ni & 1) << 4) + kb0)) & 15u;
                const float4 mf = *(const float4*)&LUTf[nib][0];
                lsum[mi] = fmaf(exp2f(acc[mi][ni][0]), mf.x, lsum[mi]);
                lsum[mi] = fmaf(exp2f(acc[mi][ni][1]), mf.y, lsum[mi]);
                lsum[mi] = fmaf(exp2f(acc[mi][ni][2]), mf.z, lsum[mi]);
                lsum[mi] = fmaf(exp2f(acc[mi][ni][3]), mf.w, lsum[mi]);
            }
        }
        __syncthreads();
    }

    // stage sweep-2 tile 0 (K and V) while reducing lsum
    stageK(0, 0);
    stageV(0, 0);

    f16x2 rlp[2];
#pragma unroll
    for (int mi = 0; mi < 2; ++mi) {
        float s = lsum[mi];
        s += __shfl_xor(s, 16);
        s += __shfl_xor(s, 32);
        const f16 rlh = (f16)(1.0f / s);
        rlp[mi][0] = rlh; rlp[mi][1] = rlh;
    }

    f32x4 accP[2][4];
#pragma unroll
    for (int mi = 0; mi < 2; ++mi)
#pragma unroll
        for (int ni = 0; ni < 4; ++ni) accP[mi][ni] = (f32x4){0.f, 0.f, 0.f, 0.f};

    float* attnBase = attn + ((size_t)b * 1024 + m0) * 16384 + h * 1024;
    const int st_r0 = tid >> 4;       // store readback: row base
    const int st_c4 = tid & 15;       // float4 column
    __syncthreads();                  // K(0), V(0) drained

    // -------- sweep 2: counted-vmcnt pipeline; stores never drained in-loop --------
    for (int j = 0; j < 16; ++j) {
        const int nb = (j + 1) & 1, jn = (j + 1) & 15;
        stageK(nb, jn);               // wraps at j=15 (harmless redundant stage of tile 0)
        stageV(nb, jn);
        // K(j),V(j) ready: 12 newer vmem ops = 8 stores of j-1 + 4 loads just issued
        asm volatile("s_waitcnt vmcnt(12) lgkmcnt(0)" ::: "memory");
        __builtin_amdgcn_s_barrier();
        __builtin_amdgcn_sched_barrier(0);

        f32x4 acc[2][4];
#pragma unroll
        for (int mi = 0; mi < 2; ++mi)
#pragma unroll
            for (int ni = 0; ni < 4; ++ni) acc[mi][ni] = (f32x4){0.f, 0.f, 0.f, 0.f};
        __builtin_amdgcn_s_setprio(1);
#pragma unroll
        for (int ks = 0; ks < 2; ++ks) {
            const int slot = ks * 4 + (lane >> 4);
            f16x8 af[2], bf[4];
#pragma unroll
            for (int mi = 0; mi < 2; ++mi) {
                const int row = w * 32 + mi * 16 + (lane & 15);
                af[mi] = *(const f16x8*)&Qs[row][(slot ^ (row & 7)) * 8];
            }
#pragma unroll
            for (int ni = 0; ni < 4; ++ni) {
                const int row = ni * 16 + (lane & 15);
                bf[ni] = *(const f16x8*)&Ks[j & 1][row][(slot ^ (row & 7)) * 8];
            }
#pragma unroll
            for (int mi = 0; mi < 2; ++mi)
#pragma unroll
                for (int ni = 0; ni < 4; ++ni)
                    acc[mi][ni] = __builtin_amdgcn_mfma_f32_16x16x32_f16(bf[ni], af[mi], acc[mi][ni], 0, 0, 0);
        }
        __builtin_amdgcn_s_setprio(0);

#pragma unroll
        for (int mi = 0; mi < 2; ++mi) {
            const int rowm = w * 32 + mi * 16 + (lane & 15);
            const int swb = (rowm & 7) << 2;
            const int swp = (rowm & 7) << 3;
#pragma unroll
            for (int ni = 0; ni < 4; ++ni) {
                const unsigned word = bm[rowm][(2 * j + (ni >> 1)) ^ swb];
                const unsigned nib = (word >> (((ni & 1) << 4) + kb0)) & 15u;
                const f16x4 mh = *(const f16x4*)&LUTh[nib][0];
                f16x2 p01 = cvt_pk_f16(exp2f(acc[mi][ni][0]), exp2f(acc[mi][ni][1]));
                f16x2 p23 = cvt_pk_f16(exp2f(acc[mi][ni][2]), exp2f(acc[mi][ni][3]));
                p01 = p01 * (f16x2){mh[0], mh[1]} * rlp[mi];
                p23 = p23 * (f16x2){mh[2], mh[3]} * rlp[mi];
                f16x4 pw; pw[0] = p01[0]; pw[1] = p01[1]; pw[2] = p23[0]; pw[3] = p23[1];
                *(f16x4*)&Ps[rowm][(ni * 16 + kb0) ^ swp] = pw;
            }
        }
        // Ps visible to all waves; LDS-only ordering (stores stay in flight)
        asm volatile("s_waitcnt lgkmcnt(0)" ::: "memory");
        __builtin_amdgcn_s_barrier();
        __builtin_amdgcn_sched_barrier(0);

        // PV MFMA (normalized P)
        __builtin_amdgcn_s_setprio(1);
#pragma unroll
        for (int ks = 0; ks < 2; ++ks) {
            const int slot = ks * 4 + (lane >> 4);
            f16x8 pf[2], vf[4];
#pragma unroll
            for (int mi = 0; mi < 2; ++mi) {
                const int row = w * 32 + mi * 16 + (lane & 15);
                pf[mi] = *(const f16x8*)&Ps[row][(slot ^ (row & 7)) * 8];
            }
#pragma unroll
            for (int ni = 0; ni < 4; ++ni) {
                const int row = ni * 16 + (lane & 15);
                vf[ni] = *(const f16x8*)&Vs[j & 1][row][(slot ^ (row & 7)) * 8];
            }
#pragma unroll
            for (int mi = 0; mi < 2; ++mi)
#pragma unroll
                for (int ni = 0; ni < 4; ++ni)
                    accP[mi][ni] = __builtin_amdgcn_mfma_f32_16x16x32_f16(pf[mi], vf[ni], accP[mi][ni], 0, 0, 0);
        }
        __builtin_amdgcn_s_setprio(0);

        // coalesced p store from Ps (256B per 16 lanes); drains under next iteration
#pragma unroll
        for (int i = 0; i < 8; ++i) {
            const int row = st_r0 + 16 * i;
            const f16x4 hv = *(const f16x4*)((const char*)&Ps[row][0] +
                    ((st_c4 >> 1) ^ (row & 7)) * 16 + (st_c4 & 1) * 8);
            f32x4 fv = {(float)hv[0], (float)hv[1], (float)hv[2], (float)hv[3]};
            __builtin_nontemporal_store(fv,
                    (f32x4*)&attnBase[(size_t)row * 16384 + j * 64 + st_c4 * 4]);
        }
    }

#pragma unroll
    for (int mi = 0; mi < 2; ++mi)
#pragma unroll
        for (int ni = 0; ni < 4; ++ni) {
            const int row0 = m0 + w * 32 + mi * 16 + ((lane >> 4) << 2);
            const int col = ni * 16 + (lane & 15);
#pragma unroll
            for (int r = 0; r < 4; ++r)
                headcat[((size_t)b * 1024 + row0 + r) * 1024 + h * 64 + col] = (f16)accP[mi][ni][r];
        }
}

extern "C" void kernel_launch(void* const* d_in, const int* in_sizes, int n_in,
                              void* d_out, int out_size, void* d_ws, size_t ws_size,
                              hipStream_t stream) {
    const float* q = (const float*)d_in[0];
    const float* k = (const float*)d_in[1];
    const float* v = (const float*)d_in[2];
    const int* mask = (const int*)d_in[3];
    const float* Wq = (const float*)d_in[4];
    const float* Wk = (const float*)d_in[5];
    const float* Wv = (const float*)d_in[6];
    const float* Wo = (const float*)d_in[7];
    const float* bo = (const float*)d_in[8];

    float* out0 = (float*)d_out;                  // [8,1024,1024]
    float* attn = out0 + (size_t)8 * 1024 * 1024; // [8,1024,16384]

    char* ws = (char*)d_ws;
    f16* wt   = (f16*)(ws + ((size_t)0 << 20));   // wqt,wkt,wvt,wot contiguous: 8 MiB
    f16* qh   = (f16*)(ws + ((size_t)8 << 20));   // q,k,v f16 contiguous: 48 MiB
    f16* Qp   = (f16*)(ws + ((size_t)56 << 20));  // Qp,Kp,VpT contiguous: 48 MiB
    f16* Kp   = (f16*)(ws + ((size_t)72 << 20));
    f16* VpT  = (f16*)(ws + ((size_t)88 << 20));
    f16* hc   = (f16*)(ws + ((size_t)104 << 20)); // [B*L, 1024] f16
    unsigned* bits = (unsigned*)(ws + ((size_t)120 << 20)); // 1 MiB bitmask
    f16* wot  = wt + (size_t)3 * 1048576;

    cvt3_kernel<<<dim3(4096, 3), 256, 0, stream>>>(q, k, v, qh);
    transpose_w_kernel<<<dim3(4096, 4), 256, 0, stream>>>(Wq, Wk, Wv, Wo, wt);
    maskbits_kernel<<<1024, 256, 0, stream>>>(mask, bits);

    proj_kernel<<<1536, 256, 0, stream>>>(qh, wt, Qp);

    attn_fused_kernel<<<1024, 256, 0, stream>>>(Qp, Kp, VpT, bits, attn, hc);

    out_kernel<<<512, 256, 0, stream>>>(hc, wot, out0, bo);
}

// Round 10
// 292.963 us; speedup vs baseline: 1.3458x; 1.2315x over previous
//
#include <hip/hip_runtime.h>

typedef _Float16 f16;
typedef _Float16 f16x8 __attribute__((ext_vector_type(8)));
typedef _Float16 f16x4 __attribute__((ext_vector_type(4)));
typedef _Float16 f16x2 __attribute__((ext_vector_type(2)));
typedef float f32x4 __attribute__((ext_vector_type(4)));

#define GLOAD_LDS16(g, l) \
    __builtin_amdgcn_global_load_lds((const __attribute__((address_space(1))) void*)(g), \
                                     (__attribute__((address_space(3))) void*)(l), 16, 0, 0)

__device__ __forceinline__ f16x2 cvt_pk_f16(float a, float b) {
    return __builtin_bit_cast(f16x2, __builtin_amdgcn_cvt_pkrtz(a, b));
}

// 0.125 * log2(e): Qp is pre-scaled by this so attn uses exp2(acc) directly
#define SC_LOG2E 0.180336880f

// ---------------- merged prep: cvt3 (12288 blocks) | weight transpose (16384) | maskbits (1024)
__global__ __launch_bounds__(256) void prep_kernel(const float* __restrict__ q,
        const float* __restrict__ k, const float* __restrict__ v,
        const float* __restrict__ Wq, const float* __restrict__ Wk,
        const float* __restrict__ Wv, const float* __restrict__ Wo,
        const int* __restrict__ mask, f16* __restrict__ qh, f16* __restrict__ wt,
        unsigned* __restrict__ bits) {
    const int bid = blockIdx.x;
    if (bid < 12288) {
        // q,k,v f32 -> f16
        const int z = bid >> 12;
        const float* src = (z == 0) ? q : (z == 1) ? k : v;
        const size_t i = ((size_t)(bid & 4095) * 256 + threadIdx.x) * 8;
        float4 a = *(const float4*)&src[i], b2 = *(const float4*)&src[i + 4];
        f16x8 h;
        h[0] = (f16)a.x; h[1] = (f16)a.y; h[2] = (f16)a.z; h[3] = (f16)a.w;
        h[4] = (f16)b2.x; h[5] = (f16)b2.y; h[6] = (f16)b2.z; h[7] = (f16)b2.w;
        *(f16x8*)&qh[(size_t)z * 8388608 + i] = h;
    } else if (bid < 28672) {
        // weight transposes: z<3: [H,D,64] -> [N][D]; z=3: Wo [D][N] -> [N][D]
        const int t2 = bid - 12288;
        const int z = t2 >> 12;
        const int t = (t2 & 4095) * 256 + threadIdx.x;
        const int n = t >> 10, d = t & 1023;
        float val;
        if (z < 3) {
            const float* W = (z == 0) ? Wq : (z == 1) ? Wk : Wv;
            val = W[((size_t)(n >> 6) * 1024 + d) * 64 + (n & 63)];
        } else {
            val = Wo[(size_t)d * 1024 + n];
        }
        wt[(size_t)z * 1048576 + (size_t)n * 1024 + d] = (f16)val;
    } else {
        // mask int32 -> bitmask
        const int t = (bid - 28672) * 256 + threadIdx.x;
        const int4* src = (const int4*)mask + (size_t)t * 8;
        unsigned w = 0;
#pragma unroll
        for (int i = 0; i < 8; ++i) {
            int4 vv = src[i];
            w |= (vv.x != 0 ? 1u : 0u) << (i * 4 + 0);
            w |= (vv.y != 0 ? 1u : 0u) << (i * 4 + 1);
            w |= (vv.z != 0 ? 1u : 0u) << (i * 4 + 2);
            w |= (vv.w != 0 ? 1u : 0u) << (i * 4 + 3);
        }
        bits[t] = w;
    }
}

// ---------------- fused Q/K/V projection GEMM, 128x128, K=1024, XCD-colocated -----------
// z=0: Qp (scaled by SC_LOG2E), z=1: Kp, both [B,H,L,64]; z=2: VpT [B,H,64,L]
__global__ __launch_bounds__(256) void proj_kernel(const f16* __restrict__ Ah,
        const f16* __restrict__ Wt, f16* __restrict__ Outp) {
    __shared__ __align__(16) f16 As[128][64];
    __shared__ __align__(16) f16 Bs[128][64];
    const int id = blockIdx.x;
    const int z = id >> 9;
    const int id2 = id & 511;
    const int m0 = ((id2 & 7) * 8 + ((id2 >> 3) & 7)) * 128;
    const int n0 = (id2 >> 6) * 128;
    const f16* A = Ah + (size_t)z * 8388608;
    const f16* Bt = Wt + (size_t)z * 1048576;
    f16* Out = Outp + (size_t)z * 8388608;
    const int tid = threadIdx.x, lane = tid & 63;
    const int w = tid >> 6, wr = w >> 1, wc = w & 1;

    f32x4 acc[4][4];
#pragma unroll
    for (int mi = 0; mi < 4; ++mi)
#pragma unroll
        for (int ni = 0; ni < 4; ++ni) acc[mi][ni] = (f32x4){0.f, 0.f, 0.f, 0.f};

    for (int kt = 0; kt < 16; ++kt) {
        const int k0 = kt * 64;
#pragma unroll
        for (int seg = 0; seg < 4; ++seg) {
            const int ch = seg * 256 + tid, r = ch >> 3, c = ch & 7;
            GLOAD_LDS16(&A[(size_t)(m0 + r) * 1024 + k0 + (c ^ (r & 7)) * 8],
                        (char*)&As[0][0] + (seg * 256 + w * 64) * 16);
            GLOAD_LDS16(&Bt[(size_t)(n0 + r) * 1024 + k0 + (c ^ (r & 7)) * 8],
                        (char*)&Bs[0][0] + (seg * 256 + w * 64) * 16);
        }
        __syncthreads();
#pragma unroll
        for (int ks = 0; ks < 2; ++ks) {
            const int slot = ks * 4 + (lane >> 4);
            f16x8 af[4], bf[4];
#pragma unroll
            for (int mi = 0; mi < 4; ++mi) {
                const int row = wr * 64 + mi * 16 + (lane & 15);
                af[mi] = *(const f16x8*)&As[row][(slot ^ (row & 7)) * 8];
            }
#pragma unroll
            for (int ni = 0; ni < 4; ++ni) {
                const int row = wc * 64 + ni * 16 + (lane & 15);
                bf[ni] = *(const f16x8*)&Bs[row][(slot ^ (row & 7)) * 8];
            }
#pragma unroll
            for (int mi = 0; mi < 4; ++mi)
#pragma unroll
                for (int ni = 0; ni < 4; ++ni)
                    acc[mi][ni] = __builtin_amdgcn_mfma_f32_16x16x32_f16(af[mi], bf[ni], acc[mi][ni], 0, 0, 0);
        }
        __syncthreads();
    }

    const float sc = (z == 0) ? SC_LOG2E : 1.0f;
#pragma unroll
    for (int mi = 0; mi < 4; ++mi)
#pragma unroll
        for (int ni = 0; ni < 4; ++ni) {
            const int row0 = m0 + wr * 64 + mi * 16 + ((lane >> 4) << 2);
            const int col = n0 + wc * 64 + ni * 16 + (lane & 15);
            const int h = col >> 6, kk = col & 63;
            const int b = row0 >> 10, l0 = row0 & 1023;
            if (z < 2) {
#pragma unroll
                for (int r = 0; r < 4; ++r)
                    Out[(((size_t)(b * 16 + h) * 1024) + l0 + r) * 64 + kk] = (f16)(acc[mi][ni][r] * sc);
            } else {
                f16x4 hv;
#pragma unroll
                for (int r = 0; r < 4; ++r) hv[r] = (f16)acc[mi][ni][r];
                *(f16x4*)&Out[((size_t)(b * 16 + h) * 64 + kk) * 1024 + l0] = hv;
            }
        }
}

// ---------------- output projection GEMM: out0 = hc @ Wo^T + bo (f32, nt stores) --------
__global__ __launch_bounds__(256) void out_kernel(const f16* __restrict__ A,
        const f16* __restrict__ Bt, float* __restrict__ O, const float* __restrict__ bias) {
    __shared__ __align__(16) f16 As[128][64];
    __shared__ __align__(16) f16 Bs[128][64];
    const int id2 = blockIdx.x;
    const int m0 = ((id2 & 7) * 8 + ((id2 >> 3) & 7)) * 128;
    const int n0 = (id2 >> 6) * 128;
    const int tid = threadIdx.x, lane = tid & 63;
    const int w = tid >> 6, wr = w >> 1, wc = w & 1;

    f32x4 acc[4][4];
#pragma unroll
    for (int mi = 0; mi < 4; ++mi)
#pragma unroll
        for (int ni = 0; ni < 4; ++ni) acc[mi][ni] = (f32x4){0.f, 0.f, 0.f, 0.f};

    for (int kt = 0; kt < 16; ++kt) {
        const int k0 = kt * 64;
#pragma unroll
        for (int seg = 0; seg < 4; ++seg) {
            const int ch = seg * 256 + tid, r = ch >> 3, c = ch & 7;
            GLOAD_LDS16(&A[(size_t)(m0 + r) * 1024 + k0 + (c ^ (r & 7)) * 8],
                        (char*)&As[0][0] + (seg * 256 + w * 64) * 16);
            GLOAD_LDS16(&Bt[(size_t)(n0 + r) * 1024 + k0 + (c ^ (r & 7)) * 8],
                        (char*)&Bs[0][0] + (seg * 256 + w * 64) * 16);
        }
        __syncthreads();
#pragma unroll
        for (int ks = 0; ks < 2; ++ks) {
            const int slot = ks * 4 + (lane >> 4);
            f16x8 af[4], bf[4];
#pragma unroll
            for (int mi = 0; mi < 4; ++mi) {
                const int row = wr * 64 + mi * 16 + (lane & 15);
                af[mi] = *(const f16x8*)&As[row][(slot ^ (row & 7)) * 8];
            }
#pragma unroll
            for (int ni = 0; ni < 4; ++ni) {
                const int row = wc * 64 + ni * 16 + (lane & 15);
                bf[ni] = *(const f16x8*)&Bs[row][(slot ^ (row & 7)) * 8];
            }
#pragma unroll
            for (int mi = 0; mi < 4; ++mi)
#pragma unroll
                for (int ni = 0; ni < 4; ++ni)
                    acc[mi][ni] = __builtin_amdgcn_mfma_f32_16x16x32_f16(af[mi], bf[ni], acc[mi][ni], 0, 0, 0);
        }
        __syncthreads();
    }

#pragma unroll
    for (int mi = 0; mi < 4; ++mi)
#pragma unroll
        for (int ni = 0; ni < 4; ++ni) {
            const int row0 = m0 + wr * 64 + mi * 16 + ((lane >> 4) << 2);
            const int col = n0 + wc * 64 + ni * 16 + (lane & 15);
            const float bb = bias[col];
#pragma unroll
            for (int r = 0; r < 4; ++r)
                __builtin_nontemporal_store(acc[mi][ni][r] + bb, &O[(size_t)(row0 + r) * 1024 + col]);
        }
}

// ---------------- fused attention: swapped QK^T, packed epilogues, nibble-LUT mask -------
// (exact R7 structure: two-sweep recompute, K dbuf + V single-buffer, plain __syncthreads)
__global__ __launch_bounds__(256) void attn_fused_kernel(const f16* __restrict__ Qp,
        const f16* __restrict__ Kp, const f16* __restrict__ VpT,
        const unsigned* __restrict__ bits, float* __restrict__ attn, f16* __restrict__ headcat) {
    __shared__ __align__(16) f16 Qs[128][64];
    __shared__ __align__(16) f16 Ks[2][64][64];
    __shared__ __align__(16) f16 Vs[64][64];          // single buffer
    __shared__ __align__(16) f16 Ps[128][64];
    __shared__ unsigned bm[128][32];                  // word w stored at w ^ ((row&7)<<2)
    __shared__ __align__(16) float LUTf[16][4];
    __shared__ __align__(16) f16 LUTh[16][4];
    const int bh = blockIdx.x & 127, m0 = (blockIdx.x >> 7) * 128;
    const int b = bh >> 4, h = bh & 15;
    const int tid = threadIdx.x, lane = tid & 63, w = tid >> 6;
    const f16* Qbase = Qp + (size_t)bh * 65536;
    const f16* Kbase = Kp + (size_t)bh * 65536;
    const f16* Vbase = VpT + (size_t)bh * 65536;

    auto stageK = [&](int buf, int j) {
#pragma unroll
        for (int seg = 0; seg < 2; ++seg) {
            const int ch = seg * 256 + tid, r = ch >> 3, c = ch & 7;
            GLOAD_LDS16(&Kbase[(size_t)(j * 64 + r) * 64 + (c ^ (r & 7)) * 8],
                        (char*)&Ks[buf][0][0] + (seg * 256 + w * 64) * 16);
        }
    };
    auto stageV = [&](int j) {
#pragma unroll
        for (int seg = 0; seg < 2; ++seg) {
            const int ch = seg * 256 + tid, r = ch >> 3, c = ch & 7;
            GLOAD_LDS16(&Vbase[(size_t)r * 1024 + j * 64 + (c ^ (r & 7)) * 8],
                        (char*)&Vs[0][0] + (seg * 256 + w * 64) * 16);
        }
    };

    if (tid < 16) {
#pragma unroll
        for (int i = 0; i < 4; ++i) {
            const float on = ((tid >> i) & 1) ? 1.0f : 0.0f;
            LUTf[tid][i] = on;
            LUTh[tid][i] = (f16)on;
        }
    }
    // prologue: Qs, bm (word-swizzled), K tile 0
#pragma unroll
    for (int seg = 0; seg < 4; ++seg) {
        const int ch = seg * 256 + tid, r = ch >> 3, c = ch & 7;
        GLOAD_LDS16(&Qbase[(size_t)(m0 + r) * 64 + (c ^ (r & 7)) * 8],
                    (char*)&Qs[0][0] + (seg * 256 + w * 64) * 16);
        GLOAD_LDS16((const char*)&bits[((size_t)b * 1024 + m0 + r) * 32] + (c ^ (r & 7)) * 16,
                    (char*)&bm[0][0] + (seg * 256 + w * 64) * 16);
    }
    stageK(0, 0);
    __syncthreads();

    float lsum[2] = {0.f, 0.f};
    const int kb0 = (lane >> 4) * 4;     // thread's contiguous 4-col base (swapped layout)

    // -------- sweep 1: l = sum_col exp2(s) * mask --------
    for (int j = 0; j < 16; ++j) {
        if (j < 15) stageK((j + 1) & 1, j + 1);

        f32x4 acc[2][4];
#pragma unroll
        for (int mi = 0; mi < 2; ++mi)
#pragma unroll
            for (int ni = 0; ni < 4; ++ni) acc[mi][ni] = (f32x4){0.f, 0.f, 0.f, 0.f};
#pragma unroll
        for (int ks = 0; ks < 2; ++ks) {
            const int slot = ks * 4 + (lane >> 4);
            f16x8 af[2], bf[4];
#pragma unroll
            for (int mi = 0; mi < 2; ++mi) {
                const int row = w * 32 + mi * 16 + (lane & 15);
                af[mi] = *(const f16x8*)&Qs[row][(slot ^ (row & 7)) * 8];
            }
#pragma unroll
            for (int ni = 0; ni < 4; ++ni) {
                const int row = ni * 16 + (lane & 15);
                bf[ni] = *(const f16x8*)&Ks[j & 1][row][(slot ^ (row & 7)) * 8];
            }
            // swapped: acc = K-frag x Q-frag -> S^T (row=kcol, col=qrow)
#pragma unroll
            for (int mi = 0; mi < 2; ++mi)
#pragma unroll
                for (int ni = 0; ni < 4; ++ni)
                    acc[mi][ni] = __builtin_amdgcn_mfma_f32_16x16x32_f16(bf[ni], af[mi], acc[mi][ni], 0, 0, 0);
        }

#pragma unroll
        for (int mi = 0; mi < 2; ++mi) {
            const int rowm = w * 32 + mi * 16 + (lane & 15);
            const int swb = (rowm & 7) << 2;
#pragma unroll
            for (int ni = 0; ni < 4; ++ni) {
                const unsigned word = bm[rowm][(2 * j + (ni >> 1)) ^ swb];
                const unsigned nib = (word >> (((ni & 1) << 4) + kb0)) & 15u;
                const float4 mf = *(const float4*)&LUTf[nib][0];
                lsum[mi] = fmaf(exp2f(acc[mi][ni][0]), mf.x, lsum[mi]);
                lsum[mi] = fmaf(exp2f(acc[mi][ni][1]), mf.y, lsum[mi]);
                lsum[mi] = fmaf(exp2f(acc[mi][ni][2]), mf.z, lsum[mi]);
                lsum[mi] = fmaf(exp2f(acc[mi][ni][3]), mf.w, lsum[mi]);
            }
        }
        __syncthreads();
    }

    // stage sweep-2 K tile 0 while reducing lsum
    stageK(0, 0);

    f16x2 rlp[2];
#pragma unroll
    for (int mi = 0; mi < 2; ++mi) {
        float s = lsum[mi];
        s += __shfl_xor(s, 16);
        s += __shfl_xor(s, 32);
        const f16 rlh = (f16)(1.0f / s);
        rlp[mi][0] = rlh; rlp[mi][1] = rlh;
    }

    f32x4 accP[2][4];
#pragma unroll
    for (int mi = 0; mi < 2; ++mi)
#pragma unroll
        for (int ni = 0; ni < 4; ++ni) accP[mi][ni] = (f32x4){0.f, 0.f, 0.f, 0.f};

    float* attnBase = attn + ((size_t)b * 1024 + m0) * 16384 + h * 1024;
    const int st_r0 = tid >> 4;       // store readback: row base
    const int st_c4 = tid & 15;       // float4 column
    __syncthreads();

    // -------- sweep 2: recompute, normalized p -> Ps (packed); PV; store p from Ps --------
    for (int j = 0; j < 16; ++j) {
        if (j < 15) stageK((j + 1) & 1, j + 1);
        stageV(j);                    // single buffer; ready at mid-barrier

        f32x4 acc[2][4];
#pragma unroll
        for (int mi = 0; mi < 2; ++mi)
#pragma unroll
            for (int ni = 0; ni < 4; ++ni) acc[mi][ni] = (f32x4){0.f, 0.f, 0.f, 0.f};
#pragma unroll
        for (int ks = 0; ks < 2; ++ks) {
            const int slot = ks * 4 + (lane >> 4);
            f16x8 af[2], bf[4];
#pragma unroll
            for (int mi = 0; mi < 2; ++mi) {
                const int row = w * 32 + mi * 16 + (lane & 15);
                af[mi] = *(const f16x8*)&Qs[row][(slot ^ (row & 7)) * 8];
            }
#pragma unroll
            for (int ni = 0; ni < 4; ++ni) {
                const int row = ni * 16 + (lane & 15);
                bf[ni] = *(const f16x8*)&Ks[j & 1][row][(slot ^ (row & 7)) * 8];
            }
#pragma unroll
            for (int mi = 0; mi < 2; ++mi)
#pragma unroll
                for (int ni = 0; ni < 4; ++ni)
                    acc[mi][ni] = __builtin_amdgcn_mfma_f32_16x16x32_f16(bf[ni], af[mi], acc[mi][ni], 0, 0, 0);
        }

#pragma unroll
        for (int mi = 0; mi < 2; ++mi) {
            const int rowm = w * 32 + mi * 16 + (lane & 15);
            const int swb = (rowm & 7) << 2;
            const int swp = (rowm & 7) << 3;
#pragma unroll
            for (int ni = 0; ni < 4; ++ni) {
                const unsigned word = bm[rowm][(2 * j + (ni >> 1)) ^ swb];
                const unsigned nib = (word >> (((ni & 1) << 4) + kb0)) & 15u;
                const f16x4 mh = *(const f16x4*)&LUTh[nib][0];
                f16x2 p01 = cvt_pk_f16(exp2f(acc[mi][ni][0]), exp2f(acc[mi][ni][1]));
                f16x2 p23 = cvt_pk_f16(exp2f(acc[mi][ni][2]), exp2f(acc[mi][ni][3]));
                p01 = p01 * (f16x2){mh[0], mh[1]} * rlp[mi];
                p23 = p23 * (f16x2){mh[2], mh[3]} * rlp[mi];
                f16x4 pw; pw[0] = p01[0]; pw[1] = p01[1]; pw[2] = p23[0]; pw[3] = p23[1];
                *(f16x4*)&Ps[rowm][(ni * 16 + kb0) ^ swp] = pw;
            }
        }
        __syncthreads();   // Ps visible; Vs(j) drained

        // PV MFMA (normalized P)
#pragma unroll
        for (int ks = 0; ks < 2; ++ks) {
            const int slot = ks * 4 + (lane >> 4);
            f16x8 pf[2], vf[4];
#pragma unroll
            for (int mi = 0; mi < 2; ++mi) {
                const int row = w * 32 + mi * 16 + (lane & 15);
                pf[mi] = *(const f16x8*)&Ps[row][(slot ^ (row & 7)) * 8];
            }
#pragma unroll
            for (int ni = 0; ni < 4; ++ni) {
                const int row = ni * 16 + (lane & 15);
                vf[ni] = *(const f16x8*)&Vs[row][(slot ^ (row & 7)) * 8];
            }
#pragma unroll
            for (int mi = 0; mi < 2; ++mi)
#pragma unroll
                for (int ni = 0; ni < 4; ++ni)
                    accP[mi][ni] = __builtin_amdgcn_mfma_f32_16x16x32_f16(pf[mi], vf[ni], accP[mi][ni], 0, 0, 0);
        }

        // coalesced p store from Ps (256B per 16 lanes), overlaps MFMA
#pragma unroll
        for (int i = 0; i < 8; ++i) {
            const int row = st_r0 + 16 * i;
            const f16x4 hv = *(const f16x4*)((const char*)&Ps[row][0] +
                    ((st_c4 >> 1) ^ (row & 7)) * 16 + (st_c4 & 1) * 8);
            f32x4 fv = {(float)hv[0], (float)hv[1], (float)hv[2], (float)hv[3]};
            __builtin_nontemporal_store(fv,
                    (f32x4*)&attnBase[(size_t)row * 16384 + j * 64 + st_c4 * 4]);
        }
        __syncthreads();
    }

#pragma unroll
    for (int mi = 0; mi < 2; ++mi)
#pragma unroll
        for (int ni = 0; ni < 4; ++ni) {
            const int row0 = m0 + w * 32 + mi * 16 + ((lane >> 4) << 2);
            const int col = ni * 16 + (lane & 15);
#pragma unroll
            for (int r = 0; r < 4; ++r)
                headcat[((size_t)b * 1024 + row0 + r) * 1024 + h * 64 + col] = (f16)accP[mi][ni][r];
        }
}

extern "C" void kernel_launch(void* const* d_in, const int* in_sizes, int n_in,
                              void* d_out, int out_size, void* d_ws, size_t ws_size,
                              hipStream_t stream) {
    const float* q = (const float*)d_in[0];
    const float* k = (const float*)d_in[1];
    const float* v = (const float*)d_in[2];
    const int* mask = (const int*)d_in[3];
    const float* Wq = (const float*)d_in[4];
    const float* Wk = (const float*)d_in[5];
    const float* Wv = (const float*)d_in[6];
    const float* Wo = (const float*)d_in[7];
    const float* bo = (const float*)d_in[8];

    float* out0 = (float*)d_out;                  // [8,1024,1024]
    float* attn = out0 + (size_t)8 * 1024 * 1024; // [8,1024,16384]

    char* ws = (char*)d_ws;
    f16* wt   = (f16*)(ws + ((size_t)0 << 20));   // wqt,wkt,wvt,wot contiguous: 8 MiB
    f16* qh   = (f16*)(ws + ((size_t)8 << 20));   // q,k,v f16 contiguous: 48 MiB
    f16* Qp   = (f16*)(ws + ((size_t)56 << 20));  // Qp,Kp,VpT contiguous: 48 MiB
    f16* Kp   = (f16*)(ws + ((size_t)72 << 20));
    f16* VpT  = (f16*)(ws + ((size_t)88 << 20));
    f16* hc   = (f16*)(ws + ((size_t)104 << 20)); // [B*L, 1024] f16
    unsigned* bits = (unsigned*)(ws + ((size_t)120 << 20)); // 1 MiB bitmask
    f16* wot  = wt + (size_t)3 * 1048576;

    prep_kernel<<<29696, 256, 0, stream>>>(q, k, v, Wq, Wk, Wv, Wo, mask, qh, wt, bits);

    proj_kernel<<<1536, 256, 0, stream>>>(qh, wt, Qp);

    attn_fused_kernel<<<1024, 256, 0, stream>>>(Qp, Kp, VpT, bits, attn, hc);

    out_kernel<<<512, 256, 0, stream>>>(hc, wot, out0, bo);
}

// Round 11
// 283.880 us; speedup vs baseline: 1.3888x; 1.0320x over previous
//
#include <hip/hip_runtime.h>

typedef _Float16 f16;
typedef _Float16 f16x8 __attribute__((ext_vector_type(8)));
typedef _Float16 f16x4 __attribute__((ext_vector_type(4)));
typedef _Float16 f16x2 __attribute__((ext_vector_type(2)));
typedef float f32x4 __attribute__((ext_vector_type(4)));

#define GLOAD_LDS16(g, l) \
    __builtin_amdgcn_global_load_lds((const __attribute__((address_space(1))) void*)(g), \
                                     (__attribute__((address_space(3))) void*)(l), 16, 0, 0)

__device__ __forceinline__ f16x2 cvt_pk_f16(float a, float b) {
    return __builtin_bit_cast(f16x2, __builtin_amdgcn_cvt_pkrtz(a, b));
}

// 0.125 * log2(e): Qp is pre-scaled by this so attn uses exp2(acc) directly
#define SC_LOG2E 0.180336880f

// ---------------- merged prep: cvt3 (12288 blocks) | weight transpose (16384) | maskbits (1024)
__global__ __launch_bounds__(256) void prep_kernel(const float* __restrict__ q,
        const float* __restrict__ k, const float* __restrict__ v,
        const float* __restrict__ Wq, const float* __restrict__ Wk,
        const float* __restrict__ Wv, const float* __restrict__ Wo,
        const int* __restrict__ mask, f16* __restrict__ qh, f16* __restrict__ wt,
        unsigned* __restrict__ bits) {
    const int bid = blockIdx.x;
    if (bid < 12288) {
        const int z = bid >> 12;
        const float* src = (z == 0) ? q : (z == 1) ? k : v;
        const size_t i = ((size_t)(bid & 4095) * 256 + threadIdx.x) * 8;
        float4 a = *(const float4*)&src[i], b2 = *(const float4*)&src[i + 4];
        f16x8 h;
        h[0] = (f16)a.x; h[1] = (f16)a.y; h[2] = (f16)a.z; h[3] = (f16)a.w;
        h[4] = (f16)b2.x; h[5] = (f16)b2.y; h[6] = (f16)b2.z; h[7] = (f16)b2.w;
        *(f16x8*)&qh[(size_t)z * 8388608 + i] = h;
    } else if (bid < 28672) {
        const int t2 = bid - 12288;
        const int z = t2 >> 12;
        const int t = (t2 & 4095) * 256 + threadIdx.x;
        const int n = t >> 10, d = t & 1023;
        float val;
        if (z < 3) {
            const float* W = (z == 0) ? Wq : (z == 1) ? Wk : Wv;
            val = W[((size_t)(n >> 6) * 1024 + d) * 64 + (n & 63)];
        } else {
            val = Wo[(size_t)d * 1024 + n];
        }
        wt[(size_t)z * 1048576 + (size_t)n * 1024 + d] = (f16)val;
    } else {
        const int t = (bid - 28672) * 256 + threadIdx.x;
        const int4* src = (const int4*)mask + (size_t)t * 8;
        unsigned w = 0;
#pragma unroll
        for (int i = 0; i < 8; ++i) {
            int4 vv = src[i];
            w |= (vv.x != 0 ? 1u : 0u) << (i * 4 + 0);
            w |= (vv.y != 0 ? 1u : 0u) << (i * 4 + 1);
            w |= (vv.z != 0 ? 1u : 0u) << (i * 4 + 2);
            w |= (vv.w != 0 ? 1u : 0u) << (i * 4 + 3);
        }
        bits[t] = w;
    }
}

// ---------------- fused Q/K/V projection GEMM, 128x128, K=1024, XCD-colocated -----------
__global__ __launch_bounds__(256) void proj_kernel(const f16* __restrict__ Ah,
        const f16* __restrict__ Wt, f16* __restrict__ Outp) {
    __shared__ __align__(16) f16 As[128][64];
    __shared__ __align__(16) f16 Bs[128][64];
    const int id = blockIdx.x;
    const int z = id >> 9;
    const int id2 = id & 511;
    const int m0 = ((id2 & 7) * 8 + ((id2 >> 3) & 7)) * 128;
    const int n0 = (id2 >> 6) * 128;
    const f16* A = Ah + (size_t)z * 8388608;
    const f16* Bt = Wt + (size_t)z * 1048576;
    f16* Out = Outp + (size_t)z * 8388608;
    const int tid = threadIdx.x, lane = tid & 63;
    const int w = tid >> 6, wr = w >> 1, wc = w & 1;

    f32x4 acc[4][4];
#pragma unroll
    for (int mi = 0; mi < 4; ++mi)
#pragma unroll
        for (int ni = 0; ni < 4; ++ni) acc[mi][ni] = (f32x4){0.f, 0.f, 0.f, 0.f};

    for (int kt = 0; kt < 16; ++kt) {
        const int k0 = kt * 64;
#pragma unroll
        for (int seg = 0; seg < 4; ++seg) {
            const int ch = seg * 256 + tid, r = ch >> 3, c = ch & 7;
            GLOAD_LDS16(&A[(size_t)(m0 + r) * 1024 + k0 + (c ^ (r & 7)) * 8],
                        (char*)&As[0][0] + (seg * 256 + w * 64) * 16);
            GLOAD_LDS16(&Bt[(size_t)(n0 + r) * 1024 + k0 + (c ^ (r & 7)) * 8],
                        (char*)&Bs[0][0] + (seg * 256 + w * 64) * 16);
        }
        __syncthreads();
#pragma unroll
        for (int ks = 0; ks < 2; ++ks) {
            const int slot = ks * 4 + (lane >> 4);
            f16x8 af[4], bf[4];
#pragma unroll
            for (int mi = 0; mi < 4; ++mi) {
                const int row = wr * 64 + mi * 16 + (lane & 15);
                af[mi] = *(const f16x8*)&As[row][(slot ^ (row & 7)) * 8];
            }
#pragma unroll
            for (int ni = 0; ni < 4; ++ni) {
                const int row = wc * 64 + ni * 16 + (lane & 15);
                bf[ni] = *(const f16x8*)&Bs[row][(slot ^ (row & 7)) * 8];
            }
#pragma unroll
            for (int mi = 0; mi < 4; ++mi)
#pragma unroll
                for (int ni = 0; ni < 4; ++ni)
                    acc[mi][ni] = __builtin_amdgcn_mfma_f32_16x16x32_f16(af[mi], bf[ni], acc[mi][ni], 0, 0, 0);
        }
        __syncthreads();
    }

    const float sc = (z == 0) ? SC_LOG2E : 1.0f;
#pragma unroll
    for (int mi = 0; mi < 4; ++mi)
#pragma unroll
        for (int ni = 0; ni < 4; ++ni) {
            const int row0 = m0 + wr * 64 + mi * 16 + ((lane >> 4) << 2);
            const int col = n0 + wc * 64 + ni * 16 + (lane & 15);
            const int h = col >> 6, kk = col & 63;
            const int b = row0 >> 10, l0 = row0 & 1023;
            if (z < 2) {
#pragma unroll
                for (int r = 0; r < 4; ++r)
                    Out[(((size_t)(b * 16 + h) * 1024) + l0 + r) * 64 + kk] = (f16)(acc[mi][ni][r] * sc);
            } else {
                f16x4 hv;
#pragma unroll
                for (int r = 0; r < 4; ++r) hv[r] = (f16)acc[mi][ni][r];
                *(f16x4*)&Out[((size_t)(b * 16 + h) * 64 + kk) * 1024 + l0] = hv;
            }
        }
}

// ---------------- output projection GEMM: out0 = hc @ Wo^T + bo (f32, nt stores) --------
__global__ __launch_bounds__(256) void out_kernel(const f16* __restrict__ A,
        const f16* __restrict__ Bt, float* __restrict__ O, const float* __restrict__ bias) {
    __shared__ __align__(16) f16 As[128][64];
    __shared__ __align__(16) f16 Bs[128][64];
    const int id2 = blockIdx.x;
    const int m0 = ((id2 & 7) * 8 + ((id2 >> 3) & 7)) * 128;
    const int n0 = (id2 >> 6) * 128;
    const int tid = threadIdx.x, lane = tid & 63;
    const int w = tid >> 6, wr = w >> 1, wc = w & 1;

    f32x4 acc[4][4];
#pragma unroll
    for (int mi = 0; mi < 4; ++mi)
#pragma unroll
        for (int ni = 0; ni < 4; ++ni) acc[mi][ni] = (f32x4){0.f, 0.f, 0.f, 0.f};

    for (int kt = 0; kt < 16; ++kt) {
        const int k0 = kt * 64;
#pragma unroll
        for (int seg = 0; seg < 4; ++seg) {
            const int ch = seg * 256 + tid, r = ch >> 3, c = ch & 7;
            GLOAD_LDS16(&A[(size_t)(m0 + r) * 1024 + k0 + (c ^ (r & 7)) * 8],
                        (char*)&As[0][0] + (seg * 256 + w * 64) * 16);
            GLOAD_LDS16(&Bt[(size_t)(n0 + r) * 1024 + k0 + (c ^ (r & 7)) * 8],
                        (char*)&Bs[0][0] + (seg * 256 + w * 64) * 16);
        }
        __syncthreads();
#pragma unroll
        for (int ks = 0; ks < 2; ++ks) {
            const int slot = ks * 4 + (lane >> 4);
            f16x8 af[4], bf[4];
#pragma unroll
            for (int mi = 0; mi < 4; ++mi) {
                const int row = wr * 64 + mi * 16 + (lane & 15);
                af[mi] = *(const f16x8*)&As[row][(slot ^ (row & 7)) * 8];
            }
#pragma unroll
            for (int ni = 0; ni < 4; ++ni) {
                const int row = wc * 64 + ni * 16 + (lane & 15);
                bf[ni] = *(const f16x8*)&Bs[row][(slot ^ (row & 7)) * 8];
            }
#pragma unroll
            for (int mi = 0; mi < 4; ++mi)
#pragma unroll
                for (int ni = 0; ni < 4; ++ni)
                    acc[mi][ni] = __builtin_amdgcn_mfma_f32_16x16x32_f16(af[mi], bf[ni], acc[mi][ni], 0, 0, 0);
        }
        __syncthreads();
    }

#pragma unroll
    for (int mi = 0; mi < 4; ++mi)
#pragma unroll
        for (int ni = 0; ni < 4; ++ni) {
            const int row0 = m0 + wr * 64 + mi * 16 + ((lane >> 4) << 2);
            const int col = n0 + wc * 64 + ni * 16 + (lane & 15);
            const float bb = bias[col];
#pragma unroll
            for (int r = 0; r < 4; ++r)
                __builtin_nontemporal_store(acc[mi][ni][r] + bb, &O[(size_t)(row0 + r) * 1024 + col]);
        }
}

// ---------------- fused attention: R7 structure at 512 threads (8 waves, 16 rows/wave) ---
__global__ __launch_bounds__(512, 4) void attn_fused_kernel(const f16* __restrict__ Qp,
        const f16* __restrict__ Kp, const f16* __restrict__ VpT,
        const unsigned* __restrict__ bits, float* __restrict__ attn, f16* __restrict__ headcat) {
    __shared__ __align__(16) f16 Qs[128][64];
    __shared__ __align__(16) f16 Ks[2][64][64];
    __shared__ __align__(16) f16 Vs[64][64];          // single buffer
    __shared__ __align__(16) f16 Ps[128][64];
    __shared__ unsigned bm[128][32];                  // word w stored at w ^ ((row&7)<<2)
    __shared__ __align__(16) float LUTf[16][4];
    __shared__ __align__(16) f16 LUTh[16][4];
    const int bh = blockIdx.x & 127, m0 = (blockIdx.x >> 7) * 128;
    const int b = bh >> 4, h = bh & 15;
    const int tid = threadIdx.x, lane = tid & 63, w = tid >> 6;  // w in [0,8)
    const int l15 = lane & 15, t4 = lane >> 4;
    const f16* Qbase = Qp + (size_t)bh * 65536;
    const f16* Kbase = Kp + (size_t)bh * 65536;
    const f16* Vbase = VpT + (size_t)bh * 65536;

    auto stageK = [&](int buf, int j) {      // 512 chunks, one per thread
        const int r = tid >> 3, c = tid & 7;
        GLOAD_LDS16(&Kbase[(size_t)(j * 64 + r) * 64 + (c ^ (r & 7)) * 8],
                    (char*)&Ks[buf][0][0] + (size_t)tid * 16);
    };
    auto stageV = [&](int j) {
        const int r = tid >> 3, c = tid & 7;
        GLOAD_LDS16(&Vbase[(size_t)r * 1024 + j * 64 + (c ^ (r & 7)) * 8],
                    (char*)&Vs[0][0] + (size_t)tid * 16);
    };

    if (tid < 16) {
#pragma unroll
        for (int i = 0; i < 4; ++i) {
            const float on = ((tid >> i) & 1) ? 1.0f : 0.0f;
            LUTf[tid][i] = on;
            LUTh[tid][i] = (f16)on;
        }
    }
    // prologue: Qs (16 KB), bm (16 KB, word-swizzled), K tile 0
#pragma unroll
    for (int seg = 0; seg < 2; ++seg) {
        const int ch = seg * 512 + tid, r = ch >> 3, c = ch & 7;
        GLOAD_LDS16(&Qbase[(size_t)(m0 + r) * 64 + (c ^ (r & 7)) * 8],
                    (char*)&Qs[0][0] + (size_t)ch * 16);
        GLOAD_LDS16((const char*)&bits[((size_t)b * 1024 + m0 + r) * 32] + (c ^ (r & 7)) * 16,
                    (char*)&bm[0][0] + (size_t)ch * 16);
    }
    stageK(0, 0);
    __syncthreads();

    const int rowm = w * 16 + l15;       // this thread's q-row (swapped S^T layout)
    const int swb = (rowm & 7) << 2;
    const int swp = (rowm & 7) << 3;
    const int kb0 = t4 * 4;              // contiguous 4-k-col base
    float lsA = 0.f, lsB = 0.f;          // split accumulators (break fma chain)

    // -------- sweep 1: l = sum_col exp2(s) * mask --------
    for (int j = 0; j < 16; ++j) {
        if (j < 15) stageK((j + 1) & 1, j + 1);

        f32x4 acc[4];
#pragma unroll
        for (int ni = 0; ni < 4; ++ni) acc[ni] = (f32x4){0.f, 0.f, 0.f, 0.f};
#pragma unroll
        for (int ks = 0; ks < 2; ++ks) {
            const int slot = ks * 4 + t4;
            const f16x8 af = *(const f16x8*)&Qs[rowm][(slot ^ (rowm & 7)) * 8];
#pragma unroll
            for (int ni = 0; ni < 4; ++ni) {
                const int row = ni * 16 + l15;
                const f16x8 bf = *(const f16x8*)&Ks[j & 1][row][(slot ^ (row & 7)) * 8];
                acc[ni] = __builtin_amdgcn_mfma_f32_16x16x32_f16(bf, af, acc[ni], 0, 0, 0);
            }
        }

#pragma unroll
        for (int ni = 0; ni < 4; ++ni) {
            const unsigned word = bm[rowm][(2 * j + (ni >> 1)) ^ swb];
            const unsigned nib = (word >> (((ni & 1) << 4) + kb0)) & 15u;
            const float4 mf = *(const float4*)&LUTf[nib][0];
            lsA = fmaf(exp2f(acc[ni][0]), mf.x, lsA);
            lsB = fmaf(exp2f(acc[ni][1]), mf.y, lsB);
            lsA = fmaf(exp2f(acc[ni][2]), mf.z, lsA);
            lsB = fmaf(exp2f(acc[ni][3]), mf.w, lsB);
        }
        __syncthreads();
    }

    // stage sweep-2 K tile 0 while reducing lsum
    stageK(0, 0);

    f16x2 rlp;
    {
        float s = lsA + lsB;
        s += __shfl_xor(s, 16);
        s += __shfl_xor(s, 32);
        const f16 rlh = (f16)(1.0f / s);
        rlp[0] = rlh; rlp[1] = rlh;
    }

    f32x4 accP[4];
#pragma unroll
    for (int ni = 0; ni < 4; ++ni) accP[ni] = (f32x4){0.f, 0.f, 0.f, 0.f};

    float* attnBase = attn + ((size_t)b * 1024 + m0) * 16384 + h * 1024;
    const int st_r0 = tid >> 4;       // store readback: row base (0..31)
    const int st_c4 = tid & 15;       // float4 column
    __syncthreads();

    // -------- sweep 2: recompute, normalized p -> Ps (packed); PV; store p from Ps --------
    for (int j = 0; j < 16; ++j) {
        if (j < 15) stageK((j + 1) & 1, j + 1);
        stageV(j);                    // single buffer; ready at mid-barrier

        f32x4 acc[4];
#pragma unroll
        for (int ni = 0; ni < 4; ++ni) acc[ni] = (f32x4){0.f, 0.f, 0.f, 0.f};
#pragma unroll
        for (int ks = 0; ks < 2; ++ks) {
            const int slot = ks * 4 + t4;
            const f16x8 af = *(const f16x8*)&Qs[rowm][(slot ^ (rowm & 7)) * 8];
#pragma unroll
            for (int ni = 0; ni < 4; ++ni) {
                const int row = ni * 16 + l15;
                const f16x8 bf = *(const f16x8*)&Ks[j & 1][row][(slot ^ (row & 7)) * 8];
                acc[ni] = __builtin_amdgcn_mfma_f32_16x16x32_f16(bf, af, acc[ni], 0, 0, 0);
            }
        }

#pragma unroll
        for (int ni = 0; ni < 4; ++ni) {
            const unsigned word = bm[rowm][(2 * j + (ni >> 1)) ^ swb];
            const unsigned nib = (word >> (((ni & 1) << 4) + kb0)) & 15u;
            const f16x4 mh = *(const f16x4*)&LUTh[nib][0];
            f16x2 p01 = cvt_pk_f16(exp2f(acc[ni][0]), exp2f(acc[ni][1]));
            f16x2 p23 = cvt_pk_f16(exp2f(acc[ni][2]), exp2f(acc[ni][3]));
            p01 = p01 * (f16x2){mh[0], mh[1]} * rlp;
            p23 = p23 * (f16x2){mh[2], mh[3]} * rlp;
            f16x4 pw; pw[0] = p01[0]; pw[1] = p01[1]; pw[2] = p23[0]; pw[3] = p23[1];
            *(f16x4*)&Ps[rowm][(ni * 16 + kb0) ^ swp] = pw;
        }
        __syncthreads();   // Ps visible; Vs(j) drained

        // PV MFMA (normalized P)
#pragma unroll
        for (int ks = 0; ks < 2; ++ks) {
            const int slot = ks * 4 + t4;
            const f16x8 pf = *(const f16x8*)&Ps[rowm][(slot ^ (rowm & 7)) * 8];
#pragma unroll
            for (int ni = 0; ni < 4; ++ni) {
                const int row = ni * 16 + l15;
                const f16x8 vf = *(const f16x8*)&Vs[row][(slot ^ (row & 7)) * 8];
                accP[ni] = __builtin_amdgcn_mfma_f32_16x16x32_f16(pf, vf, accP[ni], 0, 0, 0);
            }
        }

        // coalesced p store from Ps (256B per 16 lanes), overlaps MFMA
#pragma unroll
        for (int i = 0; i < 4; ++i) {
            const int row = st_r0 + 32 * i;
            const f16x4 hv = *(const f16x4*)((const char*)&Ps[row][0] +
                    ((st_c4 >> 1) ^ (row & 7)) * 16 + (st_c4 & 1) * 8);
            f32x4 fv = {(float)hv[0], (float)hv[1], (float)hv[2], (float)hv[3]};
            __builtin_nontemporal_store(fv,
                    (f32x4*)&attnBase[(size_t)row * 16384 + j * 64 + st_c4 * 4]);
        }
        __syncthreads();
    }

#pragma unroll
    for (int ni = 0; ni < 4; ++ni) {
        const int row0 = m0 + w * 16 + (t4 << 2);
        const int col = ni * 16 + l15;
#pragma unroll
        for (int r = 0; r < 4; ++r)
            headcat[((size_t)b * 1024 + row0 + r) * 1024 + h * 64 + col] = (f16)accP[ni][r];
    }
}

extern "C" void kernel_launch(void* const* d_in, const int* in_sizes, int n_in,
                              void* d_out, int out_size, void* d_ws, size_t ws_size,
                              hipStream_t stream) {
    const float* q = (const float*)d_in[0];
    const float* k = (const float*)d_in[1];
    const float* v = (const float*)d_in[2];
    const int* mask = (const int*)d_in[3];
    const float* Wq = (const float*)d_in[4];
    const float* Wk = (const float*)d_in[5];
    const float* Wv = (const float*)d_in[6];
    const float* Wo = (const float*)d_in[7];
    const float* bo = (const float*)d_in[8];

    float* out0 = (float*)d_out;                  // [8,1024,1024]
    float* attn = out0 + (size_t)8 * 1024 * 1024; // [8,1024,16384]

    char* ws = (char*)d_ws;
    f16* wt   = (f16*)(ws + ((size_t)0 << 20));   // wqt,wkt,wvt,wot contiguous: 8 MiB
    f16* qh   = (f16*)(ws + ((size_t)8 << 20));   // q,k,v f16 contiguous: 48 MiB
    f16* Qp   = (f16*)(ws + ((size_t)56 << 20));  // Qp,Kp,VpT contiguous: 48 MiB
    f16* Kp   = (f16*)(ws + ((size_t)72 << 20));
    f16* VpT  = (f16*)(ws + ((size_t)88 << 20));
    f16* hc   = (f16*)(ws + ((size_t)104 << 20)); // [B*L, 1024] f16
    unsigned* bits = (unsigned*)(ws + ((size_t)120 << 20)); // 1 MiB bitmask
    f16* wot  = wt + (size_t)3 * 1048576;

    prep_kernel<<<29696, 256, 0, stream>>>(q, k, v, Wq, Wk, Wv, Wo, mask, qh, wt, bits);

    proj_kernel<<<1536, 256, 0, stream>>>(qh, wt, Qp);

    attn_fused_kernel<<<1024, 512, 0, stream>>>(Qp, Kp, VpT, bits, attn, hc);

    out_kernel<<<512, 256, 0, stream>>>(hc, wot, out0, bo);
}

// Round 12
// 272.050 us; speedup vs baseline: 1.4492x; 1.0435x over previous
//
#include <hip/hip_runtime.h>

typedef _Float16 f16;
typedef _Float16 f16x8 __attribute__((ext_vector_type(8)));
typedef _Float16 f16x4 __attribute__((ext_vector_type(4)));
typedef _Float16 f16x2 __attribute__((ext_vector_type(2)));
typedef float f32x4 __attribute__((ext_vector_type(4)));

#define GLOAD_LDS16(g, l) \
    __builtin_amdgcn_global_load_lds((const __attribute__((address_space(1))) void*)(g), \
                                     (__attribute__((address_space(3))) void*)(l), 16, 0, 0)

__device__ __forceinline__ f16x2 cvt_pk_f16(float a, float b) {
    return __builtin_bit_cast(f16x2, __builtin_amdgcn_cvt_pkrtz(a, b));
}

// 0.125 * log2(e): Qp is pre-scaled by this so attn uses exp2(acc) directly
#define SC_LOG2E 0.180336880f

// ---------------- merged prep ----------------
// bid<12288: q/k/v cvt | <13056: Wq/Wk/Wv LDS-transpose | <13312: Wo LDS-transpose | rest: maskbits
__global__ __launch_bounds__(256) void prep_kernel(const float* __restrict__ q,
        const float* __restrict__ k, const float* __restrict__ v,
        const float* __restrict__ Wq, const float* __restrict__ Wk,
        const float* __restrict__ Wv, const float* __restrict__ Wo,
        const int* __restrict__ mask, f16* __restrict__ qh, f16* __restrict__ wt,
        unsigned* __restrict__ bits) {
    __shared__ float tile[64][68];
    const int bid = blockIdx.x;
    const int tid = threadIdx.x;
    if (bid < 12288) {
        const int z = bid >> 12;
        const float* src = (z == 0) ? q : (z == 1) ? k : v;
        const size_t i = ((size_t)(bid & 4095) * 256 + tid) * 8;
        float4 a = *(const float4*)&src[i], b2 = *(const float4*)&src[i + 4];
        f16x8 h;
        h[0] = (f16)a.x; h[1] = (f16)a.y; h[2] = (f16)a.z; h[3] = (f16)a.w;
        h[4] = (f16)b2.x; h[5] = (f16)b2.y; h[6] = (f16)b2.z; h[7] = (f16)b2.w;
        *(f16x8*)&qh[(size_t)z * 8388608 + i] = h;
    } else if (bid < 13056) {
        // Wq/Wk/Wv: [h, d, kk] -> wt[z][n=h*64+kk][d], 64x64 tile over (d, kk)
        const int t2 = bid - 12288;
        const int z = t2 >> 8;
        const int rem = t2 & 255;
        const int h = rem >> 4, d0 = (rem & 15) * 64;
        const float* W = (z == 0) ? Wq : (z == 1) ? Wk : Wv;
        const int rr = tid >> 4, c4 = (tid & 15) * 4;
#pragma unroll
        for (int i = 0; i < 4; ++i) {
            const int dd = rr + 16 * i;
            *(float4*)&tile[dd][c4] = *(const float4*)&W[((size_t)h * 1024 + d0 + dd) * 64 + c4];
        }
        __syncthreads();
#pragma unroll
        for (int i = 0; i < 4; ++i) {
            const int kk = rr + 16 * i;
            f16x4 hv;
            hv[0] = (f16)tile[c4 + 0][kk];
            hv[1] = (f16)tile[c4 + 1][kk];
            hv[2] = (f16)tile[c4 + 2][kk];
            hv[3] = (f16)tile[c4 + 3][kk];
            *(f16x4*)&wt[(size_t)z * 1048576 + (size_t)(h * 64 + kk) * 1024 + d0 + c4] = hv;
        }
    } else if (bid < 13312) {
        // Wo: [d][n] -> wt[3][n][d], 64x64 tile over (d, n)
        const int rem = bid - 13056;
        const int d0 = (rem >> 4) * 64, n0 = (rem & 15) * 64;
        const int rr = tid >> 4, c4 = (tid & 15) * 4;
#pragma unroll
        for (int i = 0; i < 4; ++i) {
            const int dd = rr + 16 * i;
            *(float4*)&tile[dd][c4] = *(const float4*)&Wo[(size_t)(d0 + dd) * 1024 + n0 + c4];
        }
        __syncthreads();
#pragma unroll
        for (int i = 0; i < 4; ++i) {
            const int nn = rr + 16 * i;
            f16x4 hv;
            hv[0] = (f16)tile[c4 + 0][nn];
            hv[1] = (f16)tile[c4 + 1][nn];
            hv[2] = (f16)tile[c4 + 2][nn];
            hv[3] = (f16)tile[c4 + 3][nn];
            *(f16x4*)&wt[(size_t)3 * 1048576 + (size_t)(n0 + nn) * 1024 + d0 + c4] = hv;
        }
    } else {
        const int t = (bid - 13312) * 256 + tid;
        const int4* src = (const int4*)mask + (size_t)t * 8;
        unsigned w = 0;
#pragma unroll
        for (int i = 0; i < 8; ++i) {
            int4 vv = src[i];
            w |= (vv.x != 0 ? 1u : 0u) << (i * 4 + 0);
            w |= (vv.y != 0 ? 1u : 0u) << (i * 4 + 1);
            w |= (vv.z != 0 ? 1u : 0u) << (i * 4 + 2);
            w |= (vv.w != 0 ? 1u : 0u) << (i * 4 + 3);
        }
        bits[t] = w;
    }
}

// ---------------- fused Q/K/V projection GEMM, 128x128, K=1024, XCD-colocated -----------
__global__ __launch_bounds__(256) void proj_kernel(const f16* __restrict__ Ah,
        const f16* __restrict__ Wt, f16* __restrict__ Outp) {
    __shared__ __align__(16) f16 As[128][64];
    __shared__ __align__(16) f16 Bs[128][64];
    const int id = blockIdx.x;
    const int z = id >> 9;
    const int id2 = id & 511;
    const int m0 = ((id2 & 7) * 8 + ((id2 >> 3) & 7)) * 128;
    const int n0 = (id2 >> 6) * 128;
    const f16* A = Ah + (size_t)z * 8388608;
    const f16* Bt = Wt + (size_t)z * 1048576;
    f16* Out = Outp + (size_t)z * 8388608;
    const int tid = threadIdx.x, lane = tid & 63;
    const int w = tid >> 6, wr = w >> 1, wc = w & 1;

    f32x4 acc[4][4];
#pragma unroll
    for (int mi = 0; mi < 4; ++mi)
#pragma unroll
        for (int ni = 0; ni < 4; ++ni) acc[mi][ni] = (f32x4){0.f, 0.f, 0.f, 0.f};

    for (int kt = 0; kt < 16; ++kt) {
        const int k0 = kt * 64;
#pragma unroll
        for (int seg = 0; seg < 4; ++seg) {
            const int ch = seg * 256 + tid, r = ch >> 3, c = ch & 7;
            GLOAD_LDS16(&A[(size_t)(m0 + r) * 1024 + k0 + (c ^ (r & 7)) * 8],
                        (char*)&As[0][0] + (seg * 256 + w * 64) * 16);
            GLOAD_LDS16(&Bt[(size_t)(n0 + r) * 1024 + k0 + (c ^ (r & 7)) * 8],
                        (char*)&Bs[0][0] + (seg * 256 + w * 64) * 16);
        }
        __syncthreads();
#pragma unroll
        for (int ks = 0; ks < 2; ++ks) {
            const int slot = ks * 4 + (lane >> 4);
            f16x8 af[4], bf[4];
#pragma unroll
            for (int mi = 0; mi < 4; ++mi) {
                const int row = wr * 64 + mi * 16 + (lane & 15);
                af[mi] = *(const f16x8*)&As[row][(slot ^ (row & 7)) * 8];
            }
#pragma unroll
            for (int ni = 0; ni < 4; ++ni) {
                const int row = wc * 64 + ni * 16 + (lane & 15);
                bf[ni] = *(const f16x8*)&Bs[row][(slot ^ (row & 7)) * 8];
            }
#pragma unroll
            for (int mi = 0; mi < 4; ++mi)
#pragma unroll
                for (int ni = 0; ni < 4; ++ni)
                    acc[mi][ni] = __builtin_amdgcn_mfma_f32_16x16x32_f16(af[mi], bf[ni], acc[mi][ni], 0, 0, 0);
        }
        __syncthreads();
    }

    const float sc = (z == 0) ? SC_LOG2E : 1.0f;
#pragma unroll
    for (int mi = 0; mi < 4; ++mi)
#pragma unroll
        for (int ni = 0; ni < 4; ++ni) {
            const int row0 = m0 + wr * 64 + mi * 16 + ((lane >> 4) << 2);
            const int col = n0 + wc * 64 + ni * 16 + (lane & 15);
            const int h = col >> 6, kk = col & 63;
            const int b = row0 >> 10, l0 = row0 & 1023;
            if (z < 2) {
#pragma unroll
                for (int r = 0; r < 4; ++r)
                    Out[(((size_t)(b * 16 + h) * 1024) + l0 + r) * 64 + kk] = (f16)(acc[mi][ni][r] * sc);
            } else {
                f16x4 hv;
#pragma unroll
                for (int r = 0; r < 4; ++r) hv[r] = (f16)acc[mi][ni][r];
                *(f16x4*)&Out[((size_t)(b * 16 + h) * 64 + kk) * 1024 + l0] = hv;
            }
        }
}

// ---------------- output projection GEMM: out0 = hc @ Wo^T + bo (f32, nt stores) --------
__global__ __launch_bounds__(256) void out_kernel(const f16* __restrict__ A,
        const f16* __restrict__ Bt, float* __restrict__ O, const float* __restrict__ bias) {
    __shared__ __align__(16) f16 As[128][64];
    __shared__ __align__(16) f16 Bs[128][64];
    const int id2 = blockIdx.x;
    const int m0 = ((id2 & 7) * 8 + ((id2 >> 3) & 7)) * 128;
    const int n0 = (id2 >> 6) * 128;
    const int tid = threadIdx.x, lane = tid & 63;
    const int w = tid >> 6, wr = w >> 1, wc = w & 1;

    f32x4 acc[4][4];
#pragma unroll
    for (int mi = 0; mi < 4; ++mi)
#pragma unroll
        for (int ni = 0; ni < 4; ++ni) acc[mi][ni] = (f32x4){0.f, 0.f, 0.f, 0.f};

    for (int kt = 0; kt < 16; ++kt) {
        const int k0 = kt * 64;
#pragma unroll
        for (int seg = 0; seg < 4; ++seg) {
            const int ch = seg * 256 + tid, r = ch >> 3, c = ch & 7;
            GLOAD_LDS16(&A[(size_t)(m0 + r) * 1024 + k0 + (c ^ (r & 7)) * 8],
                        (char*)&As[0][0] + (seg * 256 + w * 64) * 16);
            GLOAD_LDS16(&Bt[(size_t)(n0 + r) * 1024 + k0 + (c ^ (r & 7)) * 8],
                        (char*)&Bs[0][0] + (seg * 256 + w * 64) * 16);
        }
        __syncthreads();
#pragma unroll
        for (int ks = 0; ks < 2; ++ks) {
            const int slot = ks * 4 + (lane >> 4);
            f16x8 af[4], bf[4];
#pragma unroll
            for (int mi = 0; mi < 4; ++mi) {
                const int row = wr * 64 + mi * 16 + (lane & 15);
                af[mi] = *(const f16x8*)&As[row][(slot ^ (row & 7)) * 8];
            }
#pragma unroll
            for (int ni = 0; ni < 4; ++ni) {
                const int row = wc * 64 + ni * 16 + (lane & 15);
                bf[ni] = *(const f16x8*)&Bs[row][(slot ^ (row & 7)) * 8];
            }
#pragma unroll
            for (int mi = 0; mi < 4; ++mi)
#pragma unroll
                for (int ni = 0; ni < 4; ++ni)
                    acc[mi][ni] = __builtin_amdgcn_mfma_f32_16x16x32_f16(af[mi], bf[ni], acc[mi][ni], 0, 0, 0);
        }
        __syncthreads();
    }

#pragma unroll
    for (int mi = 0; mi < 4; ++mi)
#pragma unroll
        for (int ni = 0; ni < 4; ++ni) {
            const int row0 = m0 + wr * 64 + mi * 16 + ((lane >> 4) << 2);
            const int col = n0 + wc * 64 + ni * 16 + (lane & 15);
            const float bb = bias[col];
#pragma unroll
            for (int r = 0; r < 4; ++r)
                __builtin_nontemporal_store(acc[mi][ni][r] + bb, &O[(size_t)(row0 + r) * 1024 + col]);
        }
}

// ---------------- fused attention: 512 threads, Q-frags hoisted to registers ------------
__global__ __launch_bounds__(512, 4) void attn_fused_kernel(const f16* __restrict__ Qp,
        const f16* __restrict__ Kp, const f16* __restrict__ VpT,
        const unsigned* __restrict__ bits, float* __restrict__ attn, f16* __restrict__ headcat) {
    __shared__ __align__(16) f16 Qs[128][64];
    __shared__ __align__(16) f16 Ks[2][64][64];
    __shared__ __align__(16) f16 Vs[64][64];          // single buffer
    __shared__ __align__(16) f16 Ps[128][64];
    __shared__ unsigned bm[128][32];                  // word w stored at w ^ ((row&7)<<2)
    __shared__ __align__(16) float LUTf[16][4];
    __shared__ __align__(16) f16 LUTh[16][4];
    const int bh = blockIdx.x & 127, m0 = (blockIdx.x >> 7) * 128;
    const int b = bh >> 4, h = bh & 15;
    const int tid = threadIdx.x, lane = tid & 63, w = tid >> 6;  // w in [0,8)
    const int l15 = lane & 15, t4 = lane >> 4;
    const f16* Qbase = Qp + (size_t)bh * 65536;
    const f16* Kbase = Kp + (size_t)bh * 65536;
    const f16* Vbase = VpT + (size_t)bh * 65536;

    auto stageK = [&](int buf, int j) {      // 512 chunks, one per thread
        const int r = tid >> 3, c = tid & 7;
        GLOAD_LDS16(&Kbase[(size_t)(j * 64 + r) * 64 + (c ^ (r & 7)) * 8],
                    (char*)&Ks[buf][0][0] + (size_t)tid * 16);
    };
    auto stageV = [&](int j) {
        const int r = tid >> 3, c = tid & 7;
        GLOAD_LDS16(&Vbase[(size_t)r * 1024 + j * 64 + (c ^ (r & 7)) * 8],
                    (char*)&Vs[0][0] + (size_t)tid * 16);
    };

    if (tid < 16) {
#pragma unroll
        for (int i = 0; i < 4; ++i) {
            const float on = ((tid >> i) & 1) ? 1.0f : 0.0f;
            LUTf[tid][i] = on;
            LUTh[tid][i] = (f16)on;
        }
    }
    // prologue: Qs (16 KB), bm (16 KB, word-swizzled), K tile 0
#pragma unroll
    for (int seg = 0; seg < 2; ++seg) {
        const int ch = seg * 512 + tid, r = ch >> 3, c = ch & 7;
        GLOAD_LDS16(&Qbase[(size_t)(m0 + r) * 64 + (c ^ (r & 7)) * 8],
                    (char*)&Qs[0][0] + (size_t)ch * 16);
        GLOAD_LDS16((const char*)&bits[((size_t)b * 1024 + m0 + r) * 32] + (c ^ (r & 7)) * 16,
                    (char*)&bm[0][0] + (size_t)ch * 16);
    }
    stageK(0, 0);
    __syncthreads();

    const int rowm = w * 16 + l15;       // this thread's q-row (swapped S^T layout)
    const int swb = (rowm & 7) << 2;
    const int swp = (rowm & 7) << 3;
    const int kb0 = t4 * 4;              // contiguous 4-k-col base
    // Q fragments are loop-invariant: hoist once into registers (survive barriers)
    const f16x8 afA = *(const f16x8*)&Qs[rowm][(t4 ^ (rowm & 7)) * 8];
    const f16x8 afB = *(const f16x8*)&Qs[rowm][((4 + t4) ^ (rowm & 7)) * 8];
    float lsA = 0.f, lsB = 0.f;          // split accumulators (break fma chain)

    // -------- sweep 1: l = sum_col exp2(s) * mask --------
    for (int j = 0; j < 16; ++j) {
        if (j < 15) stageK((j + 1) & 1, j + 1);

        f32x4 acc[4];
#pragma unroll
        for (int ni = 0; ni < 4; ++ni) acc[ni] = (f32x4){0.f, 0.f, 0.f, 0.f};
#pragma unroll
        for (int ks = 0; ks < 2; ++ks) {
            const int slot = ks * 4 + t4;
            const f16x8 af = ks ? afB : afA;
#pragma unroll
            for (int ni = 0; ni < 4; ++ni) {
                const int row = ni * 16 + l15;
                const f16x8 bf = *(const f16x8*)&Ks[j & 1][row][(slot ^ (row & 7)) * 8];
                acc[ni] = __builtin_amdgcn_mfma_f32_16x16x32_f16(bf, af, acc[ni], 0, 0, 0);
            }
        }

#pragma unroll
        for (int ni = 0; ni < 4; ++ni) {
            const unsigned word = bm[rowm][(2 * j + (ni >> 1)) ^ swb];
            const unsigned nib = (word >> (((ni & 1) << 4) + kb0)) & 15u;
            const float4 mf = *(const float4*)&LUTf[nib][0];
            lsA = fmaf(exp2f(acc[ni][0]), mf.x, lsA);
            lsB = fmaf(exp2f(acc[ni][1]), mf.y, lsB);
            lsA = fmaf(exp2f(acc[ni][2]), mf.z, lsA);
            lsB = fmaf(exp2f(acc[ni][3]), mf.w, lsB);
        }
        __syncthreads();
    }

    // stage sweep-2 K tile 0 while reducing lsum
    stageK(0, 0);

    f16x2 rlp;
    {
        float s = lsA + lsB;
        s += __shfl_xor(s, 16);
        s += __shfl_xor(s, 32);
        const f16 rlh = (f16)(1.0f / s);
        rlp[0] = rlh; rlp[1] = rlh;
    }

    f32x4 accP[4];
#pragma unroll
    for (int ni = 0; ni < 4; ++ni) accP[ni] = (f32x4){0.f, 0.f, 0.f, 0.f};

    float* attnBase = attn + ((size_t)b * 1024 + m0) * 16384 + h * 1024;
    const int st_r0 = tid >> 4;       // store readback: row base (0..31)
    const int st_c4 = tid & 15;       // float4 column
    __syncthreads();

    // -------- sweep 2: recompute, normalized p -> Ps (packed); PV; store p from Ps --------
    for (int j = 0; j < 16; ++j) {
        if (j < 15) stageK((j + 1) & 1, j + 1);
        stageV(j);                    // single buffer; ready at mid-barrier

        f32x4 acc[4];
#pragma unroll
        for (int ni = 0; ni < 4; ++ni) acc[ni] = (f32x4){0.f, 0.f, 0.f, 0.f};
#pragma unroll
        for (int ks = 0; ks < 2; ++ks) {
            const int slot = ks * 4 + t4;
            const f16x8 af = ks ? afB : afA;
#pragma unroll
            for (int ni = 0; ni < 4; ++ni) {
                const int row = ni * 16 + l15;
                const f16x8 bf = *(const f16x8*)&Ks[j & 1][row][(slot ^ (row & 7)) * 8];
                acc[ni] = __builtin_amdgcn_mfma_f32_16x16x32_f16(bf, af, acc[ni], 0, 0, 0);
            }
        }

#pragma unroll
        for (int ni = 0; ni < 4; ++ni) {
            const unsigned word = bm[rowm][(2 * j + (ni >> 1)) ^ swb];
            const unsigned nib = (word >> (((ni & 1) << 4) + kb0)) & 15u;
            const f16x4 mh = *(const f16x4*)&LUTh[nib][0];
            f16x2 p01 = cvt_pk_f16(exp2f(acc[ni][0]), exp2f(acc[ni][1]));
            f16x2 p23 = cvt_pk_f16(exp2f(acc[ni][2]), exp2f(acc[ni][3]));
            p01 = p01 * (f16x2){mh[0], mh[1]} * rlp;
            p23 = p23 * (f16x2){mh[2], mh[3]} * rlp;
            f16x4 pw; pw[0] = p01[0]; pw[1] = p01[1]; pw[2] = p23[0]; pw[3] = p23[1];
            *(f16x4*)&Ps[rowm][(ni * 16 + kb0) ^ swp] = pw;
        }
        __syncthreads();   // Ps visible; Vs(j) drained

        // PV MFMA (normalized P)
#pragma unroll
        for (int ks = 0; ks < 2; ++ks) {
            const int slot = ks * 4 + t4;
            const f16x8 pf = *(const f16x8*)&Ps[rowm][(slot ^ (rowm & 7)) * 8];
#pragma unroll
            for (int ni = 0; ni < 4; ++ni) {
                const int row = ni * 16 + l15;
                const f16x8 vf = *(const f16x8*)&Vs[row][(slot ^ (row & 7)) * 8];
                accP[ni] = __builtin_amdgcn_mfma_f32_16x16x32_f16(pf, vf, accP[ni], 0, 0, 0);
            }
        }

        // coalesced p store from Ps (256B per 16 lanes), overlaps MFMA
#pragma unroll
        for (int i = 0; i < 4; ++i) {
            const int row = st_r0 + 32 * i;
            const f16x4 hv = *(const f16x4*)((const char*)&Ps[row][0] +
                    ((st_c4 >> 1) ^ (row & 7)) * 16 + (st_c4 & 1) * 8);
            f32x4 fv = {(float)hv[0], (float)hv[1], (float)hv[2], (float)hv[3]};
            __builtin_nontemporal_store(fv,
                    (f32x4*)&attnBase[(size_t)row * 16384 + j * 64 + st_c4 * 4]);
        }
        __syncthreads();
    }

#pragma unroll
    for (int ni = 0; ni < 4; ++ni) {
        const int row0 = m0 + w * 16 + (t4 << 2);
        const int col = ni * 16 + l15;
#pragma unroll
        for (int r = 0; r < 4; ++r)
            headcat[((size_t)b * 1024 + row0 + r) * 1024 + h * 64 + col] = (f16)accP[ni][r];
    }
}

extern "C" void kernel_launch(void* const* d_in, const int* in_sizes, int n_in,
                              void* d_out, int out_size, void* d_ws, size_t ws_size,
                              hipStream_t stream) {
    const float* q = (const float*)d_in[0];
    const float* k = (const float*)d_in[1];
    const float* v = (const float*)d_in[2];
    const int* mask = (const int*)d_in[3];
    const float* Wq = (const float*)d_in[4];
    const float* Wk = (const float*)d_in[5];
    const float* Wv = (const float*)d_in[6];
    const float* Wo = (const float*)d_in[7];
    const float* bo = (const float*)d_in[8];

    float* out0 = (float*)d_out;                  // [8,1024,1024]
    float* attn = out0 + (size_t)8 * 1024 * 1024; // [8,1024,16384]

    char* ws = (char*)d_ws;
    f16* wt   = (f16*)(ws + ((size_t)0 << 20));   // wqt,wkt,wvt,wot contiguous: 8 MiB
    f16* qh   = (f16*)(ws + ((size_t)8 << 20));   // q,k,v f16 contiguous: 48 MiB
    f16* Qp   = (f16*)(ws + ((size_t)56 << 20));  // Qp,Kp,VpT contiguous: 48 MiB
    f16* Kp   = (f16*)(ws + ((size_t)72 << 20));
    f16* VpT  = (f16*)(ws + ((size_t)88 << 20));
    f16* hc   = (f16*)(ws + ((size_t)104 << 20)); // [B*L, 1024] f16
    unsigned* bits = (unsigned*)(ws + ((size_t)120 << 20)); // 1 MiB bitmask
    f16* wot  = wt + (size_t)3 * 1048576;

    prep_kernel<<<14336, 256, 0, stream>>>(q, k, v, Wq, Wk, Wv, Wo, mask, qh, wt, bits);

    proj_kernel<<<1536, 256, 0, stream>>>(qh, wt, Qp);

    attn_fused_kernel<<<1024, 512, 0, stream>>>(Qp, Kp, VpT, bits, attn, hc);

    out_kernel<<<512, 256, 0, stream>>>(hc, wot, out0, bo);
}

// Round 13
// 271.125 us; speedup vs baseline: 1.4542x; 1.0034x over previous
//
#include <hip/hip_runtime.h>

typedef _Float16 f16;
typedef _Float16 f16x8 __attribute__((ext_vector_type(8)));
typedef _Float16 f16x4 __attribute__((ext_vector_type(4)));
typedef _Float16 f16x2 __attribute__((ext_vector_type(2)));
typedef float f32x4 __attribute__((ext_vector_type(4)));

#define GLOAD_LDS16(g, l) \
    __builtin_amdgcn_global_load_lds((const __attribute__((address_space(1))) void*)(g), \
                                     (__attribute__((address_space(3))) void*)(l), 16, 0, 0)

__device__ __forceinline__ f16x2 cvt_pk_f16(float a, float b) {
    return __builtin_bit_cast(f16x2, __builtin_amdgcn_cvt_pkrtz(a, b));
}

// 0.125 * log2(e): Qp is pre-scaled by this so attn uses exp2(acc) directly
#define SC_LOG2E 0.180336880f

// ---------------- merged prep (no maskbits — that overlaps with proj) ----------------
// bid<12288: q/k/v cvt | <13056: Wq/Wk/Wv LDS-transpose | <13312: Wo LDS-transpose
__global__ __launch_bounds__(256) void prep_kernel(const float* __restrict__ q,
        const float* __restrict__ k, const float* __restrict__ v,
        const float* __restrict__ Wq, const float* __restrict__ Wk,
        const float* __restrict__ Wv, const float* __restrict__ Wo,
        f16* __restrict__ qh, f16* __restrict__ wt) {
    __shared__ float tile[64][68];
    const int bid = blockIdx.x;
    const int tid = threadIdx.x;
    if (bid < 12288) {
        const int z = bid >> 12;
        const float* src = (z == 0) ? q : (z == 1) ? k : v;
        const size_t i = ((size_t)(bid & 4095) * 256 + tid) * 8;
        float4 a = *(const float4*)&src[i], b2 = *(const float4*)&src[i + 4];
        f16x8 h;
        h[0] = (f16)a.x; h[1] = (f16)a.y; h[2] = (f16)a.z; h[3] = (f16)a.w;
        h[4] = (f16)b2.x; h[5] = (f16)b2.y; h[6] = (f16)b2.z; h[7] = (f16)b2.w;
        *(f16x8*)&qh[(size_t)z * 8388608 + i] = h;
    } else if (bid < 13056) {
        // Wq/Wk/Wv: [h, d, kk] -> wt[z][n=h*64+kk][d], 64x64 tile over (d, kk)
        const int t2 = bid - 12288;
        const int z = t2 >> 8;
        const int rem = t2 & 255;
        const int h = rem >> 4, d0 = (rem & 15) * 64;
        const float* W = (z == 0) ? Wq : (z == 1) ? Wk : Wv;
        const int rr = tid >> 4, c4 = (tid & 15) * 4;
#pragma unroll
        for (int i = 0; i < 4; ++i) {
            const int dd = rr + 16 * i;
            *(float4*)&tile[dd][c4] = *(const float4*)&W[((size_t)h * 1024 + d0 + dd) * 64 + c4];
        }
        __syncthreads();
#pragma unroll
        for (int i = 0; i < 4; ++i) {
            const int kk = rr + 16 * i;
            f16x4 hv;
            hv[0] = (f16)tile[c4 + 0][kk];
            hv[1] = (f16)tile[c4 + 1][kk];
            hv[2] = (f16)tile[c4 + 2][kk];
            hv[3] = (f16)tile[c4 + 3][kk];
            *(f16x4*)&wt[(size_t)z * 1048576 + (size_t)(h * 64 + kk) * 1024 + d0 + c4] = hv;
        }
    } else {
        // Wo: [d][n] -> wt[3][n][d], 64x64 tile over (d, n)
        const int rem = bid - 13056;
        const int d0 = (rem >> 4) * 64, n0 = (rem & 15) * 64;
        const int rr = tid >> 4, c4 = (tid & 15) * 4;
#pragma unroll
        for (int i = 0; i < 4; ++i) {
            const int dd = rr + 16 * i;
            *(float4*)&tile[dd][c4] = *(const float4*)&Wo[(size_t)(d0 + dd) * 1024 + n0 + c4];
        }
        __syncthreads();
#pragma unroll
        for (int i = 0; i < 4; ++i) {
            const int nn = rr + 16 * i;
            f16x4 hv;
            hv[0] = (f16)tile[c4 + 0][nn];
            hv[1] = (f16)tile[c4 + 1][nn];
            hv[2] = (f16)tile[c4 + 2][nn];
            hv[3] = (f16)tile[c4 + 3][nn];
            *(f16x4*)&wt[(size_t)3 * 1048576 + (size_t)(n0 + nn) * 1024 + d0 + c4] = hv;
        }
    }
}

// ---------------- fused Q/K/V projection GEMM + overlapped maskbits -----------------
// blocks 0..1535: GEMM (z = id>>9); blocks 1536..2559: maskbits (memory-bound, rides
// under the GEMM's MFMA pipeline — bits are only consumed by the later attn launch)
__global__ __launch_bounds__(256) void proj_kernel(const f16* __restrict__ Ah,
        const f16* __restrict__ Wt, f16* __restrict__ Outp,
        const int* __restrict__ mask, unsigned* __restrict__ bits) {
    __shared__ __align__(16) f16 As[128][64];
    __shared__ __align__(16) f16 Bs[128][64];
    const int id = blockIdx.x;
    const int tid = threadIdx.x;
    if (id >= 1536) {
        const int t = (id - 1536) * 256 + tid;
        const int4* src = (const int4*)mask + (size_t)t * 8;
        unsigned w = 0;
#pragma unroll
        for (int i = 0; i < 8; ++i) {
            int4 vv = src[i];
            w |= (vv.x != 0 ? 1u : 0u) << (i * 4 + 0);
            w |= (vv.y != 0 ? 1u : 0u) << (i * 4 + 1);
            w |= (vv.z != 0 ? 1u : 0u) << (i * 4 + 2);
            w |= (vv.w != 0 ? 1u : 0u) << (i * 4 + 3);
        }
        bits[t] = w;
        return;
    }
    const int z = id >> 9;
    const int id2 = id & 511;
    const int m0 = ((id2 & 7) * 8 + ((id2 >> 3) & 7)) * 128;
    const int n0 = (id2 >> 6) * 128;
    const f16* A = Ah + (size_t)z * 8388608;
    const f16* Bt = Wt + (size_t)z * 1048576;
    f16* Out = Outp + (size_t)z * 8388608;
    const int lane = tid & 63;
    const int w = tid >> 6, wr = w >> 1, wc = w & 1;

    f32x4 acc[4][4];
#pragma unroll
    for (int mi = 0; mi < 4; ++mi)
#pragma unroll
        for (int ni = 0; ni < 4; ++ni) acc[mi][ni] = (f32x4){0.f, 0.f, 0.f, 0.f};

    for (int kt = 0; kt < 16; ++kt) {
        const int k0 = kt * 64;
#pragma unroll
        for (int seg = 0; seg < 4; ++seg) {
            const int ch = seg * 256 + tid, r = ch >> 3, c = ch & 7;
            GLOAD_LDS16(&A[(size_t)(m0 + r) * 1024 + k0 + (c ^ (r & 7)) * 8],
                        (char*)&As[0][0] + (seg * 256 + w * 64) * 16);
            GLOAD_LDS16(&Bt[(size_t)(n0 + r) * 1024 + k0 + (c ^ (r & 7)) * 8],
                        (char*)&Bs[0][0] + (seg * 256 + w * 64) * 16);
        }
        __syncthreads();
#pragma unroll
        for (int ks = 0; ks < 2; ++ks) {
            const int slot = ks * 4 + (lane >> 4);
            f16x8 af[4], bf[4];
#pragma unroll
            for (int mi = 0; mi < 4; ++mi) {
                const int row = wr * 64 + mi * 16 + (lane & 15);
                af[mi] = *(const f16x8*)&As[row][(slot ^ (row & 7)) * 8];
            }
#pragma unroll
            for (int ni = 0; ni < 4; ++ni) {
                const int row = wc * 64 + ni * 16 + (lane & 15);
                bf[ni] = *(const f16x8*)&Bs[row][(slot ^ (row & 7)) * 8];
            }
#pragma unroll
            for (int mi = 0; mi < 4; ++mi)
#pragma unroll
                for (int ni = 0; ni < 4; ++ni)
                    acc[mi][ni] = __builtin_amdgcn_mfma_f32_16x16x32_f16(af[mi], bf[ni], acc[mi][ni], 0, 0, 0);
        }
        __syncthreads();
    }

    const float sc = (z == 0) ? SC_LOG2E : 1.0f;
#pragma unroll
    for (int mi = 0; mi < 4; ++mi)
#pragma unroll
        for (int ni = 0; ni < 4; ++ni) {
            const int row0 = m0 + wr * 64 + mi * 16 + ((lane >> 4) << 2);
            const int col = n0 + wc * 64 + ni * 16 + (lane & 15);
            const int h = col >> 6, kk = col & 63;
            const int b = row0 >> 10, l0 = row0 & 1023;
            if (z < 2) {
#pragma unroll
                for (int r = 0; r < 4; ++r)
                    Out[(((size_t)(b * 16 + h) * 1024) + l0 + r) * 64 + kk] = (f16)(acc[mi][ni][r] * sc);
            } else {
                f16x4 hv;
#pragma unroll
                for (int r = 0; r < 4; ++r) hv[r] = (f16)acc[mi][ni][r];
                *(f16x4*)&Out[((size_t)(b * 16 + h) * 64 + kk) * 1024 + l0] = hv;
            }
        }
}

// ---------------- output projection GEMM: out0 = hc @ Wo^T + bo (f32, nt stores) --------
__global__ __launch_bounds__(256) void out_kernel(const f16* __restrict__ A,
        const f16* __restrict__ Bt, float* __restrict__ O, const float* __restrict__ bias) {
    __shared__ __align__(16) f16 As[128][64];
    __shared__ __align__(16) f16 Bs[128][64];
    const int id2 = blockIdx.x;
    const int m0 = ((id2 & 7) * 8 + ((id2 >> 3) & 7)) * 128;
    const int n0 = (id2 >> 6) * 128;
    const int tid = threadIdx.x, lane = tid & 63;
    const int w = tid >> 6, wr = w >> 1, wc = w & 1;

    f32x4 acc[4][4];
#pragma unroll
    for (int mi = 0; mi < 4; ++mi)
#pragma unroll
        for (int ni = 0; ni < 4; ++ni) acc[mi][ni] = (f32x4){0.f, 0.f, 0.f, 0.f};

    for (int kt = 0; kt < 16; ++kt) {
        const int k0 = kt * 64;
#pragma unroll
        for (int seg = 0; seg < 4; ++seg) {
            const int ch = seg * 256 + tid, r = ch >> 3, c = ch & 7;
            GLOAD_LDS16(&A[(size_t)(m0 + r) * 1024 + k0 + (c ^ (r & 7)) * 8],
                        (char*)&As[0][0] + (seg * 256 + w * 64) * 16);
            GLOAD_LDS16(&Bt[(size_t)(n0 + r) * 1024 + k0 + (c ^ (r & 7)) * 8],
                        (char*)&Bs[0][0] + (seg * 256 + w * 64) * 16);
        }
        __syncthreads();
#pragma unroll
        for (int ks = 0; ks < 2; ++ks) {
            const int slot = ks * 4 + (lane >> 4);
            f16x8 af[4], bf[4];
#pragma unroll
            for (int mi = 0; mi < 4; ++mi) {
                const int row = wr * 64 + mi * 16 + (lane & 15);
                af[mi] = *(const f16x8*)&As[row][(slot ^ (row & 7)) * 8];
            }
#pragma unroll
            for (int ni = 0; ni < 4; ++ni) {
                const int row = wc * 64 + ni * 16 + (lane & 15);
                bf[ni] = *(const f16x8*)&Bs[row][(slot ^ (row & 7)) * 8];
            }
#pragma unroll
            for (int mi = 0; mi < 4; ++mi)
#pragma unroll
                for (int ni = 0; ni < 4; ++ni)
                    acc[mi][ni] = __builtin_amdgcn_mfma_f32_16x16x32_f16(af[mi], bf[ni], acc[mi][ni], 0, 0, 0);
        }
        __syncthreads();
    }

#pragma unroll
    for (int mi = 0; mi < 4; ++mi)
#pragma unroll
        for (int ni = 0; ni < 4; ++ni) {
            const int row0 = m0 + wr * 64 + mi * 16 + ((lane >> 4) << 2);
            const int col = n0 + wc * 64 + ni * 16 + (lane & 15);
            const float bb = bias[col];
#pragma unroll
            for (int r = 0; r < 4; ++r)
                __builtin_nontemporal_store(acc[mi][ni][r] + bb, &O[(size_t)(row0 + r) * 1024 + col]);
        }
}

// ---------------- fused attention: 512 threads, Q-frags hoisted to registers ------------
__global__ __launch_bounds__(512, 4) void attn_fused_kernel(const f16* __restrict__ Qp,
        const f16* __restrict__ Kp, const f16* __restrict__ VpT,
        const unsigned* __restrict__ bits, float* __restrict__ attn, f16* __restrict__ headcat) {
    __shared__ __align__(16) f16 Qs[128][64];
    __shared__ __align__(16) f16 Ks[2][64][64];
    __shared__ __align__(16) f16 Vs[64][64];          // single buffer
    __shared__ __align__(16) f16 Ps[128][64];
    __shared__ unsigned bm[128][32];                  // word w stored at w ^ ((row&7)<<2)
    __shared__ __align__(16) float LUTf[16][4];
    __shared__ __align__(16) f16 LUTh[16][4];
    const int bh = blockIdx.x & 127, m0 = (blockIdx.x >> 7) * 128;
    const int b = bh >> 4, h = bh & 15;
    const int tid = threadIdx.x, lane = tid & 63, w = tid >> 6;  // w in [0,8)
    const int l15 = lane & 15, t4 = lane >> 4;
    const f16* Qbase = Qp + (size_t)bh * 65536;
    const f16* Kbase = Kp + (size_t)bh * 65536;
    const f16* Vbase = VpT + (size_t)bh * 65536;

    auto stageK = [&](int buf, int j) {      // 512 chunks, one per thread
        const int r = tid >> 3, c = tid & 7;
        GLOAD_LDS16(&Kbase[(size_t)(j * 64 + r) * 64 + (c ^ (r & 7)) * 8],
                    (char*)&Ks[buf][0][0] + (size_t)tid * 16);
    };
    auto stageV = [&](int j) {
        const int r = tid >> 3, c = tid & 7;
        GLOAD_LDS16(&Vbase[(size_t)r * 1024 + j * 64 + (c ^ (r & 7)) * 8],
                    (char*)&Vs[0][0] + (size_t)tid * 16);
    };

    if (tid < 16) {
#pragma unroll
        for (int i = 0; i < 4; ++i) {
            const float on = ((tid >> i) & 1) ? 1.0f : 0.0f;
            LUTf[tid][i] = on;
            LUTh[tid][i] = (f16)on;
        }
    }
    // prologue: Qs (16 KB), bm (16 KB, word-swizzled), K tile 0
#pragma unroll
    for (int seg = 0; seg < 2; ++seg) {
        const int ch = seg * 512 + tid, r = ch >> 3, c = ch & 7;
        GLOAD_LDS16(&Qbase[(size_t)(m0 + r) * 64 + (c ^ (r & 7)) * 8],
                    (char*)&Qs[0][0] + (size_t)ch * 16);
        GLOAD_LDS16((const char*)&bits[((size_t)b * 1024 + m0 + r) * 32] + (c ^ (r & 7)) * 16,
                    (char*)&bm[0][0] + (size_t)ch * 16);
    }
    stageK(0, 0);
    __syncthreads();

    const int rowm = w * 16 + l15;       // this thread's q-row (swapped S^T layout)
    const int swb = (rowm & 7) << 2;
    const int swp = (rowm & 7) << 3;
    const int kb0 = t4 * 4;              // contiguous 4-k-col base
    // Q fragments are loop-invariant: hoist once into registers (survive barriers)
    const f16x8 afA = *(const f16x8*)&Qs[rowm][(t4 ^ (rowm & 7)) * 8];
    const f16x8 afB = *(const f16x8*)&Qs[rowm][((4 + t4) ^ (rowm & 7)) * 8];
    float lsA = 0.f, lsB = 0.f;          // split accumulators (break fma chain)

    // -------- sweep 1: l = sum_col exp2(s) * mask --------
    for (int j = 0; j < 16; ++j) {
        if (j < 15) stageK((j + 1) & 1, j + 1);

        f32x4 acc[4];
#pragma unroll
        for (int ni = 0; ni < 4; ++ni) acc[ni] = (f32x4){0.f, 0.f, 0.f, 0.f};
#pragma unroll
        for (int ks = 0; ks < 2; ++ks) {
            const int slot = ks * 4 + t4;
            const f16x8 af = ks ? afB : afA;
#pragma unroll
            for (int ni = 0; ni < 4; ++ni) {
                const int row = ni * 16 + l15;
                const f16x8 bf = *(const f16x8*)&Ks[j & 1][row][(slot ^ (row & 7)) * 8];
                acc[ni] = __builtin_amdgcn_mfma_f32_16x16x32_f16(bf, af, acc[ni], 0, 0, 0);
            }
        }

#pragma unroll
        for (int ni = 0; ni < 4; ++ni) {
            const unsigned word = bm[rowm][(2 * j + (ni >> 1)) ^ swb];
            const unsigned nib = (word >> (((ni & 1) << 4) + kb0)) & 15u;
            const float4 mf = *(const float4*)&LUTf[nib][0];
            lsA = fmaf(exp2f(acc[ni][0]), mf.x, lsA);
            lsB = fmaf(exp2f(acc[ni][1]), mf.y, lsB);
            lsA = fmaf(exp2f(acc[ni][2]), mf.z, lsA);
            lsB = fmaf(exp2f(acc[ni][3]), mf.w, lsB);
        }
        __syncthreads();
    }

    // stage sweep-2 K tile 0 while reducing lsum
    stageK(0, 0);

    f16x2 rlp;
    {
        float s = lsA + lsB;
        s += __shfl_xor(s, 16);
        s += __shfl_xor(s, 32);
        const f16 rlh = (f16)(1.0f / s);
        rlp[0] = rlh; rlp[1] = rlh;
    }

    f32x4 accP[4];
#pragma unroll
    for (int ni = 0; ni < 4; ++ni) accP[ni] = (f32x4){0.f, 0.f, 0.f, 0.f};

    float* attnBase = attn + ((size_t)b * 1024 + m0) * 16384 + h * 1024;
    const int st_r0 = tid >> 4;       // store readback: row base (0..31)
    const int st_c4 = tid & 15;       // float4 column
    __syncthreads();

    // -------- sweep 2: recompute, normalized p -> Ps (packed); PV; store p from Ps --------
    for (int j = 0; j < 16; ++j) {
        if (j < 15) stageK((j + 1) & 1, j + 1);
        stageV(j);                    // single buffer; ready at mid-barrier

        f32x4 acc[4];
#pragma unroll
        for (int ni = 0; ni < 4; ++ni) acc[ni] = (f32x4){0.f, 0.f, 0.f, 0.f};
#pragma unroll
        for (int ks = 0; ks < 2; ++ks) {
            const int slot = ks * 4 + t4;
            const f16x8 af = ks ? afB : afA;
#pragma unroll
            for (int ni = 0; ni < 4; ++ni) {
                const int row = ni * 16 + l15;
                const f16x8 bf = *(const f16x8*)&Ks[j & 1][row][(slot ^ (row & 7)) * 8];
                acc[ni] = __builtin_amdgcn_mfma_f32_16x16x32_f16(bf, af, acc[ni], 0, 0, 0);
            }
        }

#pragma unroll
        for (int ni = 0; ni < 4; ++ni) {
            const unsigned word = bm[rowm][(2 * j + (ni >> 1)) ^ swb];
            const unsigned nib = (word >> (((ni & 1) << 4) + kb0)) & 15u;
            const f16x4 mh = *(const f16x4*)&LUTh[nib][0];
            f16x2 p01 = cvt_pk_f16(exp2f(acc[ni][0]), exp2f(acc[ni][1]));
            f16x2 p23 = cvt_pk_f16(exp2f(acc[ni][2]), exp2f(acc[ni][3]));
            p01 = p01 * (f16x2){mh[0], mh[1]} * rlp;
            p23 = p23 * (f16x2){mh[2], mh[3]} * rlp;
            f16x4 pw; pw[0] = p01[0]; pw[1] = p01[1]; pw[2] = p23[0]; pw[3] = p23[1];
            *(f16x4*)&Ps[rowm][(ni * 16 + kb0) ^ swp] = pw;
        }
        __syncthreads();   // Ps visible; Vs(j) drained

        // PV MFMA (normalized P)
#pragma unroll
        for (int ks = 0; ks < 2; ++ks) {
            const int slot = ks * 4 + t4;
            const f16x8 pf = *(const f16x8*)&Ps[rowm][(slot ^ (rowm & 7)) * 8];
#pragma unroll
            for (int ni = 0; ni < 4; ++ni) {
                const int row = ni * 16 + l15;
                const f16x8 vf = *(const f16x8*)&Vs[row][(slot ^ (row & 7)) * 8];
                accP[ni] = __builtin_amdgcn_mfma_f32_16x16x32_f16(pf, vf, accP[ni], 0, 0, 0);
            }
        }

        // coalesced p store from Ps (256B per 16 lanes), overlaps MFMA
#pragma unroll
        for (int i = 0; i < 4; ++i) {
            const int row = st_r0 + 32 * i;
            const f16x4 hv = *(const f16x4*)((const char*)&Ps[row][0] +
                    ((st_c4 >> 1) ^ (row & 7)) * 16 + (st_c4 & 1) * 8);
            f32x4 fv = {(float)hv[0], (float)hv[1], (float)hv[2], (float)hv[3]};
            __builtin_nontemporal_store(fv,
                    (f32x4*)&attnBase[(size_t)row * 16384 + j * 64 + st_c4 * 4]);
        }
        __syncthreads();
    }

#pragma unroll
    for (int ni = 0; ni < 4; ++ni) {
        const int row0 = m0 + w * 16 + (t4 << 2);
        const int col = ni * 16 + l15;
#pragma unroll
        for (int r = 0; r < 4; ++r)
            headcat[((size_t)b * 1024 + row0 + r) * 1024 + h * 64 + col] = (f16)accP[ni][r];
    }
}

extern "C" void kernel_launch(void* const* d_in, const int* in_sizes, int n_in,
                              void* d_out, int out_size, void* d_ws, size_t ws_size,
                              hipStream_t stream) {
    const float* q = (const float*)d_in[0];
    const float* k = (const float*)d_in[1];
    const float* v = (const float*)d_in[2];
    const int* mask = (const int*)d_in[3];
    const float* Wq = (const float*)d_in[4];
    const float* Wk = (const float*)d_in[5];
    const float* Wv = (const float*)d_in[6];
    const float* Wo = (const float*)d_in[7];
    const float* bo = (const float*)d_in[8];

    float* out0 = (float*)d_out;                  // [8,1024,1024]
    float* attn = out0 + (size_t)8 * 1024 * 1024; // [8,1024,16384]

    char* ws = (char*)d_ws;
    f16* wt   = (f16*)(ws + ((size_t)0 << 20));   // wqt,wkt,wvt,wot contiguous: 8 MiB
    f16* qh   = (f16*)(ws + ((size_t)8 << 20));   // q,k,v f16 contiguous: 48 MiB
    f16* Qp   = (f16*)(ws + ((size_t)56 << 20));  // Qp,Kp,VpT contiguous: 48 MiB
    f16* Kp   = (f16*)(ws + ((size_t)72 << 20));
    f16* VpT  = (f16*)(ws + ((size_t)88 << 20));
    f16* hc   = (f16*)(ws + ((size_t)104 << 20)); // [B*L, 1024] f16
    unsigned* bits = (unsigned*)(ws + ((size_t)120 << 20)); // 1 MiB bitmask
    f16* wot  = wt + (size_t)3 * 1048576;

    prep_kernel<<<13312, 256, 0, stream>>>(q, k, v, Wq, Wk, Wv, Wo, qh, wt);

    proj_kernel<<<2560, 256, 0, stream>>>(qh, wt, Qp, mask, bits);

    attn_fused_kernel<<<1024, 512, 0, stream>>>(Qp, Kp, VpT, bits, attn, hc);

    out_kernel<<<512, 256, 0, stream>>>(hc, wot, out0, bo);
}